// Round 13
// baseline (373.840 us; speedup 1.0000x reference)
//
#include <hip/hip_runtime.h>
#include <hip/hip_bf16.h>
#include <math.h>

#define SEQ 1024
#define DIM 1024
#define NH  16
#define NE  8
#define FF  4096

typedef float f32x4 __attribute__((ext_vector_type(4)));
typedef float f32x2 __attribute__((ext_vector_type(2)));
typedef short short8 __attribute__((ext_vector_type(8)));
typedef short s16x4 __attribute__((ext_vector_type(4)));

#define WAIT_VM(N) asm volatile("s_waitcnt vmcnt(" #N ")" ::: "memory")

__device__ __forceinline__ ushort f2bf(float f) {
  union { float f; unsigned u; } v; v.f = f;
  unsigned r = v.u + 0x7FFF + ((v.u >> 16) & 1);
  return (ushort)(r >> 16);
}
__device__ __forceinline__ float bf2f(ushort h) {
  union { unsigned u; float f; } v; v.u = ((unsigned)h) << 16;
  return v.f;
}

__device__ __forceinline__ float gelu_tanh(float x) {
  return 0.5f * x * (1.f + tanhf(0.7978845608028654f * (x + 0.044715f * x * x * x)));
}
__device__ __forceinline__ float gelu_fast(float x) {
  float u = 1.5957691216057308f * (x + 0.044715f * x * x * x);
  return x / (1.f + __expf(-u));
}

__device__ __forceinline__ void gl2lds16(const void* g, void* l) {
  __builtin_amdgcn_global_load_lds(
      (const __attribute__((address_space(1))) unsigned int*)g,
      (__attribute__((address_space(3))) unsigned int*)l, 16, 0, 0);
}

// ---------------------------------------------------------------------------
// Small weight convert+transpose (qkv & o-proj only, hi+lo).
// ---------------------------------------------------------------------------
__global__ __launch_bounds__(256) void wconv_kernel(
    const float* __restrict__ wq, const float* __restrict__ wo,
    ushort* __restrict__ wqT, ushort* __restrict__ wqTl,
    ushort* __restrict__ woT, ushort* __restrict__ woTl) {
  __shared__ __align__(16) ushort th[64 * 64];
  __shared__ __align__(16) ushort tl[64 * 64];
  int z = blockIdx.z, t = threadIdx.x;
  const float* src; ushort* dh; ushort* dl; int R, C, r0, c0;
  if (z == 0) {
    src = wq; dh = wqT; dl = wqTl;
    R = DIM; C = 3 * DIM; r0 = blockIdx.y * 64; c0 = blockIdx.x * 64;
  } else {
    if (blockIdx.x >= 16) return;
    src = wo; dh = woT; dl = woTl;
    R = DIM; C = DIM; r0 = blockIdx.y * 64; c0 = blockIdx.x * 64;
  }
  int ry = (t >> 4) * 4;
  int cx = (t & 15) * 4;
  f32x4 v[4];
#pragma unroll
  for (int j = 0; j < 4; j++)
    v[j] = *(const f32x4*)&src[(size_t)(r0 + ry + j) * C + c0 + cx];
#pragma unroll
  for (int i = 0; i < 4; i++) {
    int trow = cx + i;
    int o = trow * 64 + (((ry >> 3) ^ (trow & 7)) << 3) + (ry & 7);
    ushort uh[4], ul[4];
#pragma unroll
    for (int j = 0; j < 4; j++) {
      float f = v[j][i];
      ushort hh = f2bf(f);
      uh[j] = hh;
      ul[j] = f2bf(f - bf2f(hh));
    }
    *(s16x4*)&th[o] = *(const s16x4*)uh;
    *(s16x4*)&tl[o] = *(const s16x4*)ul;
  }
  __syncthreads();
  int tr = t >> 2, tc = (t & 3) * 16;
  int b0 = (tc >> 3) ^ (tr & 7);
  int b1 = ((tc >> 3) + 1) ^ (tr & 7);
  size_t dbase = (size_t)(c0 + tr) * R + r0 + tc;
  short8 u0 = *(const short8*)&th[tr * 64 + b0 * 8];
  short8 u1 = *(const short8*)&th[tr * 64 + b1 * 8];
  *(short8*)&dh[dbase] = u0;
  *(short8*)&dh[dbase + 8] = u1;
  short8 l0 = *(const short8*)&tl[tr * 64 + b0 * 8];
  short8 l1 = *(const short8*)&tl[tr * 64 + b1 * 8];
  *(short8*)&dl[dbase] = l0;
  *(short8*)&dl[dbase + 8] = l1;
}

// ---------------- fp32 -> bf16 hi/lo split (vectorized) ----------------
__global__ __launch_bounds__(256) void bfsplit_kernel(const float* __restrict__ in,
                                                      ushort* __restrict__ oh,
                                                      ushort* __restrict__ ol) {
  int i = (blockIdx.x * 256 + threadIdx.x) * 4;
  f32x4 v = *(const f32x4*)&in[i];
  ushort h[4], l[4];
#pragma unroll
  for (int j = 0; j < 4; j++) { h[j] = f2bf(v[j]); l[j] = f2bf(v[j] - bf2f(h[j])); }
  *(s16x4*)&oh[i] = *(const s16x4*)h;
  *(s16x4*)&ol[i] = *(const s16x4*)l;
}

// ---------------------------------------------------------------------------
// Fused expert GEMM, tile 256m x 128n, 512 threads (8 waves, each 64m x 64n).
// Raises arithmetic intensity to ~65 FLOP/B (per step: A 16KB bf16 + B 16KB
// fp32 for 2.1 MFLOP) — the r12 counters showed the vector path at the
// 10.2 B/cyc/CU ceiling, so fewer bytes/FLOP is the only lever.
// B fp32 [E][K][N] k-major coalesced (f32x2/thread), converted + register-
// transposed into slot-XOR-swizzled LDS [n][k] (stride 40; same formulas as
// r12, verified). Depth-2 register prefetch; one s_barrier per step.
// EPI 1: +bias +gelu -> bf16.  EPI 3: raw fp32 partial (+ ks*2048*N).
// ---------------------------------------------------------------------------
#define MM_FEXP_LOAD(ra0v, ra1v, rb0v, rb1v, rb2v, rb3v, T)            \
  { int _ko = (T) * 32;                                                \
    ra0v = *(const short8*)(aG[0] + _ko);                              \
    ra1v = *(const short8*)(aG[1] + _ko);                              \
    rb0v = *(const f32x2*)(bG + (size_t)(_ko + 0) * N);                \
    rb1v = *(const f32x2*)(bG + (size_t)(_ko + 1) * N);                \
    rb2v = *(const f32x2*)(bG + (size_t)(_ko + 2) * N);                \
    rb3v = *(const f32x2*)(bG + (size_t)(_ko + 3) * N); }

#define MM_FEXP_STAGE(buf, ra0v, ra1v, rb0v, rb1v, rb2v, rb3v)         \
  { *(short8*)&As[buf][aw[0]] = ra0v;                                  \
    *(short8*)&As[buf][aw[1]] = ra1v;                                  \
    _Pragma("unroll")                                                  \
    for (int i = 0; i < 2; i++) {                                      \
      int col = nb * 2 + i;                                            \
      ushort u[4];                                                     \
      u[0] = f2bf(rb0v[i]); u[1] = f2bf(rb1v[i]);                      \
      u[2] = f2bf(rb2v[i]); u[3] = f2bf(rb3v[i]);                      \
      *(s16x4*)&Bs[buf][col * 40 + bslot * 4] = *(const s16x4*)u; } }

#define MM_FEXP_MFMA(buf)                                              \
  { short8 af[4], bf[4];                                               \
    _Pragma("unroll")                                                  \
    for (int mi = 0; mi < 4; mi++) af[mi] = *(const short8*)&As[buf][aro[mi]]; \
    _Pragma("unroll")                                                  \
    for (int ni = 0; ni < 4; ni++) bf[ni] = *(const short8*)&Bs[buf][bro[ni]]; \
    _Pragma("unroll")                                                  \
    for (int mi = 0; mi < 4; mi++)                                     \
      _Pragma("unroll")                                                \
      for (int ni = 0; ni < 4; ni++)                                   \
        acc[mi][ni] = __builtin_amdgcn_mfma_f32_16x16x32_bf16(af[mi], bf[ni], acc[mi][ni], 0, 0, 0); }

template <int EPI, int KSPLIT>
__global__ __launch_bounds__(512) void mm_fexp(
    const ushort* __restrict__ A, const float* __restrict__ Bf,
    const float* __restrict__ bias, void* __restrict__ Cout,
    const int* __restrict__ tok, const int* __restrict__ offcnt,
    int N, int K)
{
  int zz = blockIdx.z;
  int e  = (KSPLIT > 1) ? (zz & (NE - 1)) : zz;
  int ks = (KSPLIT > 1) ? (zz >> 3) : 0;
  int off = offcnt[e], cnt = offcnt[NE + e];
  int m0 = blockIdx.y * 256;
  if (m0 >= cnt) return;
  int n0 = blockIdx.x * 128;
  const float* Bp = Bf + (size_t)e * K * N;
  const int Kc = K / KSPLIT, kbase = ks * Kc;

  __shared__ __align__(16) ushort As[2][256 * 32];
  __shared__ __align__(16) ushort Bs[2][128 * 40];

  int t = threadIdx.x, lane = t & 63, w = t >> 6;
  int wr = w >> 1, wc = w & 1;
  int g = lane >> 4, l4 = lane & 15;

  // A staging: thread covers 2 granules (16B each), XOR-preswizzled src
  const ushort* aG[2]; int aw[2];
#pragma unroll
  for (int c = 0; c < 2; c++) {
    int gid = c * 512 + t;
    int m = gid >> 2, p = gid & 3;
    int kg = p ^ ((m >> 1) & 3);
    int mc = m0 + m; if (mc > cnt - 1) mc = cnt - 1;
    int arow = tok ? tok[off + mc] : (off + mc);
    aG[c] = A + (size_t)arow * K + kbase + kg * 8;
    aw[c] = gid * 8;
  }

  // B staging: kb = k group (4 rows), nb = col-pair index (2 cols)
  int kb = t >> 6, nb = t & 63;
  const float* bG = Bp + (size_t)(kbase + kb * 4) * N + n0 + nb * 2;
  int bslot = kb ^ (((nb >> 1) & 3) << 1);

  // fragment read offsets (wave (wr,wc) owns rows wr*64.., cols wc*64..)
  int aro[4], bro[4];
#pragma unroll
  for (int mi = 0; mi < 4; mi++) {
    int m = wr * 64 + mi * 16 + l4;
    aro[mi] = (m * 4 + (g ^ ((m >> 1) & 3))) * 8;
  }
#pragma unroll
  for (int ni = 0; ni < 4; ni++) {
    int n = wc * 64 + ni * 16 + l4;
    bro[ni] = n * 40 + ((g * 2) ^ (((n >> 2) & 3) << 1)) * 4;
  }

  f32x4 acc[4][4] = {};
  const int nt = Kc / 32;   // 32 for both exp1 and exp2 — always even

  short8 raA0, raA1, raB0, raB1;
  f32x2 rbA0, rbA1, rbA2, rbA3, rbB0, rbB1, rbB2, rbB3;
  MM_FEXP_LOAD(raA0, raA1, rbA0, rbA1, rbA2, rbA3, 0);
  MM_FEXP_LOAD(raB0, raB1, rbB0, rbB1, rbB2, rbB3, 1);

  for (int tt = 0; tt < nt; tt += 2) {
    // even step: buffer 0, set A
    MM_FEXP_STAGE(0, raA0, raA1, rbA0, rbA1, rbA2, rbA3);
    if (tt + 2 < nt) MM_FEXP_LOAD(raA0, raA1, rbA0, rbA1, rbA2, rbA3, tt + 2);
    asm volatile("s_waitcnt lgkmcnt(0)" ::: "memory");
    __builtin_amdgcn_sched_barrier(0);
    __builtin_amdgcn_s_barrier();
    MM_FEXP_MFMA(0);
    // odd step: buffer 1, set B
    MM_FEXP_STAGE(1, raB0, raB1, rbB0, rbB1, rbB2, rbB3);
    if (tt + 3 < nt) MM_FEXP_LOAD(raB0, raB1, rbB0, rbB1, rbB2, rbB3, tt + 3);
    asm volatile("s_waitcnt lgkmcnt(0)" ::: "memory");
    __builtin_amdgcn_sched_barrier(0);
    __builtin_amdgcn_s_barrier();
    MM_FEXP_MFMA(1);
  }

  const float* biasp = (EPI == 3) ? nullptr : bias + (size_t)e * N;
  float* Cp = (float*)Cout + (size_t)ks * 2048 * N;
#pragma unroll
  for (int mi = 0; mi < 4; mi++) {
#pragma unroll
    for (int j = 0; j < 4; j++) {
      int grow = m0 + wr * 64 + mi * 16 + g * 4 + j;
      if (grow >= cnt) continue;
      size_t rbase = (size_t)(off + grow) * N;
#pragma unroll
      for (int ni = 0; ni < 4; ni++) {
        int gcol = n0 + wc * 64 + ni * 16 + l4;
        float v = acc[mi][ni][j];
        if (EPI == 1) ((ushort*)Cout)[rbase + gcol] = f2bf(gelu_fast(v + biasp[gcol]));
        else          Cp[rbase + gcol] = v;
      }
    }
  }
}

#undef MM_FEXP_LOAD
#undef MM_FEXP_STAGE
#undef MM_FEXP_MFMA

// ---------------------------------------------------------------------------
// Split-precision GEMM (pre-router path): A hi/lo [M][K], B hi/lo [N][K],
// C fp32 = A@B^T with 3 MFMA products (hh+hl+lh) ~ fp32 accuracy.
// ---------------------------------------------------------------------------
__global__ __launch_bounds__(256) void mm_split(
    const ushort* __restrict__ Ah, const ushort* __restrict__ Al,
    const ushort* __restrict__ Bh, const ushort* __restrict__ Bl,
    float* __restrict__ C, int N, int K)
{
  int m0 = blockIdx.y * 128;
  int n0 = blockIdx.x * 128;

  __shared__ __align__(16) ushort Ahs[2][4096], Als[2][4096];
  __shared__ __align__(16) ushort Bhs[2][4096], Bls[2][4096];

  int t = threadIdx.x, lane = t & 63, w = t >> 6, wr = w >> 1, wc = w & 1;

  const ushort *aGh[2], *aGl[2], *bGh[2], *bGl[2];
  int lofs[2];
#pragma unroll
  for (int c = 0; c < 2; c++) {
    int gid = w * 128 + c * 64 + lane;
    int m = gid >> 2, p = gid & 3;
    int kg = p ^ ((m >> 1) & 3);
    aGh[c] = Ah + (size_t)(m0 + m) * K + kg * 8;
    aGl[c] = Al + (size_t)(m0 + m) * K + kg * 8;
    bGh[c] = Bh + (size_t)(n0 + m) * K + kg * 8;
    bGl[c] = Bl + (size_t)(n0 + m) * K + kg * 8;
    lofs[c] = (w * 128 + c * 64) * 8;
  }

  int aro[4], bro[4];
#pragma unroll
  for (int mi = 0; mi < 4; mi++) {
    int m = wr * 64 + mi * 16 + (lane & 15);
    aro[mi] = (m * 4 + ((lane >> 4) ^ ((m >> 1) & 3))) * 8;
  }
#pragma unroll
  for (int ni = 0; ni < 4; ni++) {
    int n = wc * 64 + ni * 16 + (lane & 15);
    bro[ni] = (n * 4 + ((lane >> 4) ^ ((n >> 1) & 3))) * 8;
  }

  f32x4 acc[4][4] = {};
  const int nt = K / 32;

#pragma unroll
  for (int c = 0; c < 2; c++) {
    gl2lds16(aGh[c], &Ahs[0][lofs[c]]); gl2lds16(aGl[c], &Als[0][lofs[c]]);
    gl2lds16(bGh[c], &Bhs[0][lofs[c]]); gl2lds16(bGl[c], &Bls[0][lofs[c]]);
  }
  if (nt > 1) {
#pragma unroll
    for (int c = 0; c < 2; c++) {
      gl2lds16(aGh[c] + 32, &Ahs[1][lofs[c]]); gl2lds16(aGl[c] + 32, &Als[1][lofs[c]]);
      gl2lds16(bGh[c] + 32, &Bhs[1][lofs[c]]); gl2lds16(bGl[c] + 32, &Bls[1][lofs[c]]);
    }
  }

  for (int tt = 0; tt < nt; tt++) {
    if (tt + 1 < nt) WAIT_VM(8); else WAIT_VM(0);
    __builtin_amdgcn_s_barrier();
    int b = tt & 1;
    short8 ah[4], al_[4], bh[4], bl_[4];
#pragma unroll
    for (int mi = 0; mi < 4; mi++) {
      ah[mi] = *(const short8*)&Ahs[b][aro[mi]];
      al_[mi] = *(const short8*)&Als[b][aro[mi]];
    }
#pragma unroll
    for (int ni = 0; ni < 4; ni++) {
      bh[ni] = *(const short8*)&Bhs[b][bro[ni]];
      bl_[ni] = *(const short8*)&Bls[b][bro[ni]];
    }
#pragma unroll
    for (int mi = 0; mi < 4; mi++)
#pragma unroll
      for (int ni = 0; ni < 4; ni++) {
        acc[mi][ni] = __builtin_amdgcn_mfma_f32_16x16x32_bf16(al_[mi], bh[ni], acc[mi][ni], 0, 0, 0);
        acc[mi][ni] = __builtin_amdgcn_mfma_f32_16x16x32_bf16(ah[mi], bl_[ni], acc[mi][ni], 0, 0, 0);
        acc[mi][ni] = __builtin_amdgcn_mfma_f32_16x16x32_bf16(ah[mi], bh[ni], acc[mi][ni], 0, 0, 0);
      }
    asm volatile("s_waitcnt lgkmcnt(0)" ::: "memory");
    __builtin_amdgcn_sched_barrier(0);
    __builtin_amdgcn_s_barrier();
    if (tt + 2 < nt) {
      int ko = (tt + 2) * 32;
#pragma unroll
      for (int c = 0; c < 2; c++) {
        gl2lds16(aGh[c] + ko, &Ahs[b][lofs[c]]); gl2lds16(aGl[c] + ko, &Als[b][lofs[c]]);
        gl2lds16(bGh[c] + ko, &Bhs[b][lofs[c]]); gl2lds16(bGl[c] + ko, &Bls[b][lofs[c]]);
      }
    }
  }

#pragma unroll
  for (int mi = 0; mi < 4; mi++)
#pragma unroll
    for (int j = 0; j < 4; j++) {
      int grow = m0 + wr * 64 + mi * 16 + (lane >> 4) * 4 + j;
      size_t rbase = (size_t)grow * N;
#pragma unroll
      for (int ni = 0; ni < 4; ni++) {
        int gcol = n0 + wc * 64 + ni * 16 + (lane & 15);
        C[rbase + gcol] = acc[mi][ni][j];
      }
    }
}

// ---------------------------------------------------------------------------
// bf16-MFMA GEMM with in-loop conversion (fallback path only).
// ---------------------------------------------------------------------------
template <int EPI, int SPLIT>
__global__ __launch_bounds__(256) void mm_bf16(
    const float* __restrict__ A, const float* __restrict__ B,
    const float* __restrict__ bias, float* __restrict__ C,
    const int* __restrict__ tok, const int* __restrict__ offcnt,
    int M, int N, int K)
{
  int e = blockIdx.z;
  int off = 0, cnt = M;
  if (offcnt) { off = offcnt[e]; cnt = offcnt[NE + e]; }
  int m0 = blockIdx.y * 128;
  if (m0 >= cnt) return;
  const float* Bp = B + (size_t)e * K * N;
  const float* biasp = (EPI == 0) ? nullptr : bias + (size_t)e * N;
  int n0 = blockIdx.x * 128;

  __shared__ __align__(16) ushort As[(SPLIT + 1) * 128 * 32];
  __shared__ __align__(16) ushort Bs[(SPLIT + 1) * 128 * 32];

  int t = threadIdx.x;
  int lane = t & 63;
  int w = t >> 6, wr = w >> 1, wc = w & 1;

  const float* aptr[2];
  int aws[2];
  for (int i = 0; i < 2; i++) {
    int mr = i * 64 + (t >> 2);
    int mc = m0 + mr; if (mc > cnt - 1) mc = cnt - 1;
    int arow = tok ? tok[off + mc] : (off + mc);
    aptr[i] = A + (size_t)arow * K + (t & 3) * 8;
    aws[i] = mr * 32 + (t & 3) * 8;
  }

  int bn = t >> 1, bkh = (t & 1) * 16;
  const float* bptr = Bp + (size_t)bkh * N + n0 + bn;
  int bws0 = bn * 32 + 8 * (((bkh >> 3) + 0) ^ (bn & 3));
  int bws1 = bn * 32 + 8 * (((bkh >> 3) + 1) ^ (bn & 3));

  int aro[4], bro[4];
#pragma unroll
  for (int mi = 0; mi < 4; mi++)
    aro[mi] = (wr * 64 + mi * 16 + (lane & 15)) * 32 + (lane >> 4) * 8;
#pragma unroll
  for (int ni = 0; ni < 4; ni++) {
    int n = wc * 64 + ni * 16 + (lane & 15);
    bro[ni] = n * 32 + 8 * ((lane >> 4) ^ (n & 3));
  }

  f32x4 acc[4][4] = {};

  for (int k0 = 0; k0 < K; k0 += 32) {
#pragma unroll
    for (int i = 0; i < 2; i++) {
      f32x4 v0 = *(const f32x4*)(aptr[i] + k0);
      f32x4 v1 = *(const f32x4*)(aptr[i] + k0 + 4);
      ushort uh[8], ul[8];
#pragma unroll
      for (int j = 0; j < 4; j++) {
        float f0 = v0[j], f1 = v1[j];
        ushort h0 = f2bf(f0), h1 = f2bf(f1);
        uh[j] = h0; uh[4 + j] = h1;
        if (SPLIT) { ul[j] = f2bf(f0 - bf2f(h0)); ul[4 + j] = f2bf(f1 - bf2f(h1)); }
      }
      *(short8*)&As[aws[i]] = *(const short8*)uh;
      if (SPLIT) *(short8*)&As[4096 + aws[i]] = *(const short8*)ul;
    }
    {
      const float* bp = bptr + (size_t)k0 * N;
      ushort uh[16], ul[16];
#pragma unroll
      for (int i = 0; i < 16; i++) {
        float f = bp[(size_t)i * N];
        ushort h = f2bf(f);
        uh[i] = h;
        if (SPLIT) ul[i] = f2bf(f - bf2f(h));
      }
      *(short8*)&Bs[bws0] = *(const short8*)&uh[0];
      *(short8*)&Bs[bws1] = *(const short8*)&uh[8];
      if (SPLIT) {
        *(short8*)&Bs[4096 + bws0] = *(const short8*)&ul[0];
        *(short8*)&Bs[4096 + bws1] = *(const short8*)&ul[8];
      }
    }
    __syncthreads();
    short8 afh[4], bfh[4], afl[4], bfl[4];
#pragma unroll
    for (int mi = 0; mi < 4; mi++) {
      afh[mi] = *(const short8*)&As[aro[mi]];
      if (SPLIT) afl[mi] = *(const short8*)&As[4096 + aro[mi]];
    }
#pragma unroll
    for (int ni = 0; ni < 4; ni++) {
      bfh[ni] = *(const short8*)&Bs[bro[ni]];
      if (SPLIT) bfl[ni] = *(const short8*)&Bs[4096 + bro[ni]];
    }
#pragma unroll
    for (int mi = 0; mi < 4; mi++)
#pragma unroll
      for (int ni = 0; ni < 4; ni++) {
        if (SPLIT) {
          acc[mi][ni] = __builtin_amdgcn_mfma_f32_16x16x32_bf16(afl[mi], bfh[ni], acc[mi][ni], 0, 0, 0);
          acc[mi][ni] = __builtin_amdgcn_mfma_f32_16x16x32_bf16(afh[mi], bfl[ni], acc[mi][ni], 0, 0, 0);
        }
        acc[mi][ni] = __builtin_amdgcn_mfma_f32_16x16x32_bf16(afh[mi], bfh[ni], acc[mi][ni], 0, 0, 0);
      }
    __syncthreads();
  }

#pragma unroll
  for (int mi = 0; mi < 4; mi++) {
#pragma unroll
    for (int j = 0; j < 4; j++) {
      int grow = m0 + wr * 64 + mi * 16 + (lane >> 4) * 4 + j;
      if (grow >= cnt) continue;
      size_t rbase = (size_t)(off + grow) * N;
#pragma unroll
      for (int ni = 0; ni < 4; ni++) {
        int gcol = n0 + wc * 64 + ni * 16 + (lane & 15);
        float v = acc[mi][ni][j];
        if (EPI >= 1) v += biasp[gcol];
        if (EPI == 1) v = gelu_tanh(v);
        C[rbase + gcol] = v;
      }
    }
  }
}

// ---------------------------------------------------------------------------
// MFMA flash attention, split-bf16 QK^T and PV (~fp32 accuracy).
// ---------------------------------------------------------------------------
__device__ __forceinline__ int vidx(int d, int key) {
  return d * 64 + ((((key >> 3) ^ (d & 7)) << 3) | (key & 7));
}

__global__ __launch_bounds__(256, 1) void attn_mfma(const float* __restrict__ qkv,
                                                    float* __restrict__ o) {
  const int qb = blockIdx.x;
  const int head = blockIdx.y;
  const int q0 = qb * 128;
  const int t = threadIdx.x;
  const int lane = t & 63, w = t >> 6;
  const int g = lane >> 4, l4 = lane & 15;

  __shared__ __align__(16) ushort Kh[64 * 64], Kl[64 * 64];
  __shared__ __align__(16) ushort Vh[64 * 64], Vl[64 * 64];
  __shared__ __align__(16) ushort Ph[4][32 * 72], Pl[4][32 * 72];

  short8 qh[2][2], ql[2][2];
#pragma unroll
  for (int mi = 0; mi < 2; mi++)
#pragma unroll
    for (int ks = 0; ks < 2; ks++) {
      int row = q0 + w * 32 + mi * 16 + l4;
      const float* qp = qkv + (size_t)row * 3072 + head * 64 + ks * 32 + g * 8;
      f32x4 a = *(const f32x4*)qp;
      f32x4 b4 = *(const f32x4*)(qp + 4);
      ushort uh[8], ul_[8];
#pragma unroll
      for (int j = 0; j < 4; j++) {
        ushort h0 = f2bf(a[j]), h1 = f2bf(b4[j]);
        uh[j] = h0; uh[4 + j] = h1;
        ul_[j] = f2bf(a[j] - bf2f(h0)); ul_[4 + j] = f2bf(b4[j] - bf2f(h1));
      }
      qh[mi][ks] = *(const short8*)uh;
      ql[mi][ks] = *(const short8*)ul_;
    }

  float m_s[2][4], l_s[2][4];
  f32x4 O[2][4] = {};
#pragma unroll
  for (int mi = 0; mi < 2; mi++)
#pragma unroll
    for (int j = 0; j < 4; j++) { m_s[mi][j] = -INFINITY; l_s[mi][j] = 0.f; }

  const int nt = 2 * (qb + 1);
  for (int kt = 0; kt < nt; kt++) {
    const int kv0 = kt * 64;
    __syncthreads();
    {
      int key = t >> 2;
      int dblk = (t & 3) * 16;
      const float* kp = qkv + (size_t)(kv0 + key) * 3072 + 1024 + head * 64 + dblk;
      const float* vp = kp + 1024;
      f32x4 k0 = *(const f32x4*)kp, k1 = *(const f32x4*)(kp + 4),
            k2 = *(const f32x4*)(kp + 8), k3 = *(const f32x4*)(kp + 12);
      f32x4 v0 = *(const f32x4*)vp, v1 = *(const f32x4*)(vp + 4),
            v2 = *(const f32x4*)(vp + 8), v3 = *(const f32x4*)(vp + 12);
      float kf[16] = {k0[0],k0[1],k0[2],k0[3], k1[0],k1[1],k1[2],k1[3],
                      k2[0],k2[1],k2[2],k2[3], k3[0],k3[1],k3[2],k3[3]};
      float vf[16] = {v0[0],v0[1],v0[2],v0[3], v1[0],v1[1],v1[2],v1[3],
                      v2[0],v2[1],v2[2],v2[3], v3[0],v3[1],v3[2],v3[3]};
#pragma unroll
      for (int half = 0; half < 2; half++) {
        int d8 = (dblk >> 3) + half;
        int idx = key * 64 + ((d8 ^ (key & 7)) << 3);
        ushort uh[8], ul_[8];
#pragma unroll
        for (int j = 0; j < 8; j++) {
          float f = kf[half * 8 + j];
          ushort h = f2bf(f);
          uh[j] = h; ul_[j] = f2bf(f - bf2f(h));
        }
        *(short8*)&Kh[idx] = *(const short8*)uh;
        *(short8*)&Kl[idx] = *(const short8*)ul_;
      }
#pragma unroll
      for (int i = 0; i < 16; i++) {
        int d = dblk + i;
        int idx = vidx(d, key);
        float f = vf[i];
        ushort h = f2bf(f);
        Vh[idx] = h; Vl[idx] = f2bf(f - bf2f(h));
      }
    }
    __syncthreads();

    if (kv0 <= q0 + w * 32 + 31) {
      f32x4 S[2][4] = {};
#pragma unroll
      for (int ks = 0; ks < 2; ks++) {
        short8 kbh[4], kbl[4];
#pragma unroll
        for (int ni = 0; ni < 4; ni++) {
          int key = ni * 16 + l4;
          int d8 = ks * 4 + g;
          int idx = key * 64 + ((d8 ^ (key & 7)) << 3);
          kbh[ni] = *(const short8*)&Kh[idx];
          kbl[ni] = *(const short8*)&Kl[idx];
        }
#pragma unroll
        for (int mi = 0; mi < 2; mi++)
#pragma unroll
          for (int ni = 0; ni < 4; ni++) {
            S[mi][ni] = __builtin_amdgcn_mfma_f32_16x16x32_bf16(ql[mi][ks], kbh[ni], S[mi][ni], 0, 0, 0);
            S[mi][ni] = __builtin_amdgcn_mfma_f32_16x16x32_bf16(qh[mi][ks], kbl[ni], S[mi][ni], 0, 0, 0);
            S[mi][ni] = __builtin_amdgcn_mfma_f32_16x16x32_bf16(qh[mi][ks], kbh[ni], S[mi][ni], 0, 0, 0);
          }
      }
#pragma unroll
      for (int mi = 0; mi < 2; mi++) {
        int rowb = q0 + w * 32 + mi * 16 + g * 4;
        float mx[4] = {-INFINITY, -INFINITY, -INFINITY, -INFINITY};
#pragma unroll
        for (int ni = 0; ni < 4; ni++) {
          int col = kv0 + ni * 16 + l4;
#pragma unroll
          for (int j = 0; j < 4; j++) {
            float s = S[mi][ni][j] * 0.125f;
            if (col > rowb + j) s = -INFINITY;
            S[mi][ni][j] = s;
            mx[j] = fmaxf(mx[j], s);
          }
        }
#pragma unroll
        for (int j = 0; j < 4; j++) {
#pragma unroll
          for (int msk = 8; msk; msk >>= 1) mx[j] = fmaxf(mx[j], __shfl_xor(mx[j], msk));
          float mn = fmaxf(m_s[mi][j], mx[j]);
          float sc = __expf(m_s[mi][j] - mn);
          m_s[mi][j] = mn;
          l_s[mi][j] *= sc;
#pragma unroll
          for (int df = 0; df < 4; df++) O[mi][df][j] *= sc;
        }
        float ps[4] = {0.f, 0.f, 0.f, 0.f};
#pragma unroll
        for (int ni = 0; ni < 4; ni++)
#pragma unroll
          for (int j = 0; j < 4; j++) {
            float p = __expf(S[mi][ni][j] - m_s[mi][j]);
            ps[j] += p;
            int rl = mi * 16 + g * 4 + j, cl = ni * 16 + l4;
            ushort h = f2bf(p);
            Ph[w][rl * 72 + cl] = h;
            Pl[w][rl * 72 + cl] = f2bf(p - bf2f(h));
          }
#pragma unroll
        for (int j = 0; j < 4; j++) {
#pragma unroll
          for (int msk = 8; msk; msk >>= 1) ps[j] += __shfl_xor(ps[j], msk);
          l_s[mi][j] += ps[j];
        }
      }
      asm volatile("s_waitcnt lgkmcnt(0)" ::: "memory");
      __builtin_amdgcn_sched_barrier(0);
#pragma unroll
      for (int ks = 0; ks < 2; ks++) {
        short8 pah[2], pal[2], vbh[4], vbl[4];
#pragma unroll
        for (int mi = 0; mi < 2; mi++) {
          int idx = (mi * 16 + l4) * 72 + ks * 32 + g * 8;
          pah[mi] = *(const short8*)&Ph[w][idx];
          pal[mi] = *(const short8*)&Pl[w][idx];
        }
#pragma unroll
        for (int df = 0; df < 4; df++) {
          int d = df * 16 + l4;
          int k8 = ks * 4 + g;
          int idx = d * 64 + ((k8 ^ (d & 7)) << 3);
          vbh[df] = *(const short8*)&Vh[idx];
          vbl[df] = *(const short8*)&Vl[idx];
        }
#pragma unroll
        for (int mi = 0; mi < 2; mi++)
#pragma unroll
          for (int df = 0; df < 4; df++) {
            O[mi][df] = __builtin_amdgcn_mfma_f32_16x16x32_bf16(pal[mi], vbh[df], O[mi][df], 0, 0, 0);
            O[mi][df] = __builtin_amdgcn_mfma_f32_16x16x32_bf16(pah[mi], vbl[df], O[mi][df], 0, 0, 0);
            O[mi][df] = __builtin_amdgcn_mfma_f32_16x16x32_bf16(pah[mi], vbh[df], O[mi][df], 0, 0, 0);
          }
      }
    }
  }

#pragma unroll
  for (int mi = 0; mi < 2; mi++)
#pragma unroll
    for (int j = 0; j < 4; j++) {
      int row = q0 + w * 32 + mi * 16 + g * 4 + j;
      float inv = 1.f / l_s[mi][j];
#pragma unroll
      for (int df = 0; df < 4; df++)
        o[(size_t)row * DIM + head * 64 + df * 16 + l4] = O[mi][df][j] * inv;
    }
}

// ---------------- block reduce helper ----------------
__device__ float block_reduce_256(float v, float* red, int t) {
  red[t] = v; __syncthreads();
  for (int st = 128; st > 0; st >>= 1) {
    if (t < st) red[t] += red[t + st];
    __syncthreads();
  }
  float r = red[0];
  __syncthreads();
  return r;
}

// ---------------- h = LN(x + r) * g + b  (+ optional bf16 copy) ----------------
__global__ __launch_bounds__(256) void addln_kernel(const float* __restrict__ x,
                                                    const float* __restrict__ r,
                                                    const float* __restrict__ g,
                                                    const float* __restrict__ b,
                                                    float* __restrict__ out,
                                                    ushort* __restrict__ outb) {
  __shared__ float red[256];
  int row = blockIdx.x, t = threadIdx.x;
  float vals[4];
  float s = 0.f;
  for (int i = 0; i < 4; i++) {
    int d = t + i * 256;
    vals[i] = x[(size_t)row * DIM + d] + r[(size_t)row * DIM + d];
    s += vals[i];
  }
  float mean = block_reduce_256(s, red, t) * (1.f / DIM);
  float vs = 0.f;
  for (int i = 0; i < 4; i++) { float d = vals[i] - mean; vs += d * d; }
  float var = block_reduce_256(vs, red, t) * (1.f / DIM);
  float inv = rsqrtf(var + 1e-5f);
  for (int i = 0; i < 4; i++) {
    int d = t + i * 256;
    float v = (vals[i] - mean) * inv * g[d] + b[d];
    out[(size_t)row * DIM + d] = v;
    if (outb) outb[(size_t)row * DIM + d] = f2bf(v);
  }
}

// ---------------- router ----------------
__global__ __launch_bounds__(256) void router_kernel(const float* __restrict__ h,
                                                     const float* __restrict__ wg,
                                                     int* __restrict__ topi,
                                                     float* __restrict__ topw) {
  __shared__ float red[NE][256];
  int tkn = blockIdx.x, t = threadIdx.x;
  float acc[NE] = {};
  for (int i = 0; i < 4; i++) {
    int d = t + i * 256;
    float hv = h[(size_t)tkn * DIM + d];
    const float* wr = wg + (size_t)d * NE;
    for (int e = 0; e < NE; e++) acc[e] += hv * wr[e];
  }
  for (int e = 0; e < NE; e++) red[e][t] = acc[e];
  __syncthreads();
  for (int st = 128; st > 0; st >>= 1) {
    if (t < st)
      for (int e = 0; e < NE; e++) red[e][t] += red[e][t + st];
    __syncthreads();
  }
  if (t == 0) {
    float l[NE];
    for (int e = 0; e < NE; e++) l[e] = red[e][0];
    int i0 = 0;
    for (int e = 1; e < NE; e++) if (l[e] > l[i0]) i0 = e;
    int i1 = -1;
    for (int e = 0; e < NE; e++) {
      if (e == i0) continue;
      if (i1 < 0 || l[e] > l[i1]) i1 = e;
    }
    float p1 = __expf(l[i1] - l[i0]);
    float inv = 1.f / (1.f + p1);
    topi[tkn * 2] = i0; topi[tkn * 2 + 1] = i1;
    topw[tkn * 2] = inv; topw[tkn * 2 + 1] = p1 * inv;
  }
}

// ---------------- deterministic per-expert compaction (1 block) ----------------
__global__ __launch_bounds__(1024) void compact_kernel(const int* __restrict__ topi,
                                                       int* __restrict__ tok,
                                                       int* __restrict__ assign_row,
                                                       int* __restrict__ offcnt) {
  __shared__ int scan[1024];
  __shared__ int sbase;
  int t = threadIdx.x;
  if (t == 0) sbase = 0;
  __syncthreads();
  for (int e = 0; e < NE; e++) {
    int which = -1;
    if (topi[t * 2] == e) which = 0;
    else if (topi[t * 2 + 1] == e) which = 1;
    scan[t] = (which >= 0) ? 1 : 0;
    __syncthreads();
    for (int s2 = 1; s2 < 1024; s2 <<= 1) {
      int add = (t >= s2) ? scan[t - s2] : 0;
      __syncthreads();
      scan[t] += add;
      __syncthreads();
    }
    int incl = scan[t];
    int total = scan[1023];
    int base = sbase;
    if (which >= 0) {
      int pos = base + incl - 1;
      tok[pos] = t;
      assign_row[t * 2 + which] = pos;
    }
    if (t == 0) { offcnt[e] = base; offcnt[NE + e] = total; }
    __syncthreads();
    if (t == 0) sbase = base + total;
    __syncthreads();
  }
}

// ---------------- final: out = LN(h + combine(moe)) ----------------
template <int KS>
__global__ __launch_bounds__(256) void final_ln_kernel(const float* __restrict__ h,
                                                       const float* __restrict__ y,
                                                       const int* __restrict__ assign_row,
                                                       const float* __restrict__ topw,
                                                       const int* __restrict__ topi,
                                                       const float* __restrict__ bb2,
                                                       const float* __restrict__ g,
                                                       const float* __restrict__ b,
                                                       float* __restrict__ out) {
  __shared__ float red[256];
  int row = blockIdx.x, t = threadIdx.x;
  int r0 = assign_row[row * 2], r1 = assign_row[row * 2 + 1];
  float w0 = topw[row * 2], w1 = topw[row * 2 + 1];
  float vals[4];
  float s = 0.f;
  for (int i = 0; i < 4; i++) {
    int d = t + i * 256;
    float acc0 = 0.f, acc1 = 0.f;
#pragma unroll
    for (int p = 0; p < KS; p++) {
      acc0 += y[(size_t)p * 2048 * DIM + (size_t)r0 * DIM + d];
      acc1 += y[(size_t)p * 2048 * DIM + (size_t)r1 * DIM + d];
    }
    float v = h[(size_t)row * DIM + d] + w0 * acc0 + w1 * acc1;
    if (KS > 1) {
      int e0 = topi[row * 2], e1 = topi[row * 2 + 1];
      v += w0 * bb2[e0 * DIM + d] + w1 * bb2[e1 * DIM + d];
    }
    vals[i] = v;
    s += v;
  }
  float mean = block_reduce_256(s, red, t) * (1.f / DIM);
  float vs = 0.f;
  for (int i = 0; i < 4; i++) { float d = vals[i] - mean; vs += d * d; }
  float var = block_reduce_256(vs, red, t) * (1.f / DIM);
  float inv = rsqrtf(var + 1e-5f);
  for (int i = 0; i < 4; i++) {
    int d = t + i * 256;
    out[(size_t)row * DIM + d] = (vals[i] - mean) * inv * g[d] + b[d];
  }
}

extern "C" void kernel_launch(void* const* d_in, const int* in_sizes, int n_in,
                              void* d_out, int out_size, void* d_ws, size_t ws_size,
                              hipStream_t stream) {
  const float* x     = (const float*)d_in[0];
  const float* w_qkv = (const float*)d_in[1];
  const float* w_o   = (const float*)d_in[2];
  const float* g1    = (const float*)d_in[3];
  const float* b1    = (const float*)d_in[4];
  const float* wg    = (const float*)d_in[5];
  const float* w1    = (const float*)d_in[6];
  const float* bb1   = (const float*)d_in[7];
  const float* w2    = (const float*)d_in[8];
  const float* bb2   = (const float*)d_in[9];
  const float* g2    = (const float*)d_in[10];
  const float* b2    = (const float*)d_in[11];
  float* out = (float*)d_out;
  float* ws = (float*)d_ws;

  const bool fast = ws_size >= (size_t)46671872 * 4;

  if (fast) {
    float* qkv    = ws;                       // 3,145,728 f
    float* attn_o = ws + 3145728;             // 1,048,576 f
    float* oproj  = ws + 4194304;             // 1,048,576 f
    float* h      = ws + 5242880;             // 1,048,576 f
    float* ybuf   = ws + 6291456;             // 2,097,152 f (xh/xl/oh/ol aliases)
    float* topw   = ws + 8388608;             // 2,048 f
    int*   ibase  = (int*)(ws + 8390656);     // 8,192 ints
    int* topi       = ibase;
    int* tok        = ibase + 2048;
    int* assign_row = ibase + 4096;
    int* offcnt     = ibase + 6144;
    ushort* hb  = (ushort*)(ws + 8398848);    // 1,048,576 us
    ushort* h1b = (ushort*)(ws + 8923136);    // 8,388,608 us
    ushort* wqT  = (ushort*)(ws + 13117440);  // 3,145,728 us
    ushort* wqTl = wqT + 3145728;             // 3,145,728 us
    ushort* woT  = wqT + 6291456;             // 1,048,576 us
    ushort* woTl = wqT + 7340032;             // 1,048,576 us  (ends at f 17,311,744)
    float* ypart = ws + 17311744;             // 8,388,608 f (32 MB K-split partials)
    ushort* xh = (ushort*)ybuf;               // activation split aliases
    ushort* xl = xh + 1048576;
    ushort* oh = xh + 2097152;
    ushort* ol = xh + 3145728;

    // 0. small weight convert/transpose (qkv & o-proj, hi+lo)
    wconv_kernel<<<dim3(48, 16, 2), 256, 0, stream>>>(w_qkv, w_o,
                                                      wqT, wqTl, woT, woTl);
    // 0b. split x
    bfsplit_kernel<<<dim3(SEQ * DIM / 1024), 256, 0, stream>>>(x, xh, xl);
    // 1. qkv = x @ w_qkv  (pipelined split GEMM)
    mm_split<<<dim3(24, 8), 256, 0, stream>>>(xh, xl, wqT, wqTl, qkv, 3 * DIM, DIM);
    // 2. attention
    attn_mfma<<<dim3(8, NH), 256, 0, stream>>>(qkv, attn_o);
    // 2b. split attn_o
    bfsplit_kernel<<<dim3(SEQ * DIM / 1024), 256, 0, stream>>>(attn_o, oh, ol);
    // 3. oproj = attn_o @ w_o
    mm_split<<<dim3(8, 8), 256, 0, stream>>>(oh, ol, woT, woTl, oproj, DIM, DIM);
    // 4. h = LN(x + oproj), + bf16 copy
    addln_kernel<<<dim3(SEQ), 256, 0, stream>>>(x, oproj, g1, b1, h, hb);
    // 5. router
    router_kernel<<<dim3(SEQ), 256, 0, stream>>>(h, wg, topi, topw);
    // 6. compaction
    compact_kernel<<<dim3(1), 1024, 0, stream>>>(topi, tok, assign_row, offcnt);
    // 7. expert up+gelu -> bf16 (256x128 tile, 65 FLOP/B)
    mm_fexp<1, 1><<<dim3(FF / 128, 4, NE), 512, 0, stream>>>(hb, w1, bb1, (void*)h1b,
                                                             tok, offcnt, FF, DIM);
    // 8. expert down, K-split 4 -> fp32 partials (256x128 tile)
    mm_fexp<3, 4><<<dim3(DIM / 128, 4, NE * 4), 512, 0, stream>>>(h1b, w2, nullptr,
                                                                  (void*)ypart,
                                                                  nullptr, offcnt, DIM, FF);
    // 9. combine partials + bb2 + residual + LN
    final_ln_kernel<4><<<dim3(SEQ), 256, 0, stream>>>(h, ypart, assign_row, topw,
                                                      topi, bb2, g2, b2, out);
  } else {
    float* qkv    = ws;
    float* attn_o = ws + 3145728;
    float* oproj  = ws + 4194304;
    float* h      = ws + 5242880;
    float* h1     = ws + 6291456;
    float* ybuf   = ws + 14680064;
    float* topw   = ws + 16777216;
    int*   ibase  = (int*)(ws + 16779264);
    int* topi       = ibase;
    int* tok        = ibase + 2048;
    int* assign_row = ibase + 4096;
    int* offcnt     = ibase + 6144;

    mm_bf16<0, 1><<<dim3(24, 8, 1), 256, 0, stream>>>(x, w_qkv, nullptr, qkv,
                                                      nullptr, nullptr, SEQ, 3 * DIM, DIM);
    attn_mfma<<<dim3(8, NH), 256, 0, stream>>>(qkv, attn_o);
    mm_bf16<0, 1><<<dim3(8, 8, 1), 256, 0, stream>>>(attn_o, w_o, nullptr, oproj,
                                                     nullptr, nullptr, SEQ, DIM, DIM);
    addln_kernel<<<dim3(SEQ), 256, 0, stream>>>(x, oproj, g1, b1, h, nullptr);
    router_kernel<<<dim3(SEQ), 256, 0, stream>>>(h, wg, topi, topw);
    compact_kernel<<<dim3(1), 1024, 0, stream>>>(topi, tok, assign_row, offcnt);
    mm_bf16<1, 0><<<dim3(32, 8, NE), 256, 0, stream>>>(h, w1, bb1, h1,
                                                       tok, offcnt, SEQ, FF, DIM);
    mm_bf16<2, 0><<<dim3(8, 8, NE), 256, 0, stream>>>(h1, w2, bb2, ybuf,
                                                      nullptr, offcnt, SEQ, DIM, FF);
    final_ln_kernel<1><<<dim3(SEQ), 256, 0, stream>>>(h, ybuf, assign_row, topw,
                                                      nullptr, nullptr, g2, b2, out);
  }
}

// Round 14
// 313.535 us; speedup vs baseline: 1.1923x; 1.1923x over previous
//
#include <hip/hip_runtime.h>
#include <hip/hip_bf16.h>
#include <math.h>

#define SEQ 1024
#define DIM 1024
#define NH  16
#define NE  8
#define FF  4096

typedef float f32x4 __attribute__((ext_vector_type(4)));
typedef float f32x2 __attribute__((ext_vector_type(2)));
typedef short short8 __attribute__((ext_vector_type(8)));
typedef short s16x4 __attribute__((ext_vector_type(4)));

#define WAIT_VM(N) asm volatile("s_waitcnt vmcnt(" #N ")" ::: "memory")

__device__ __forceinline__ ushort f2bf(float f) {
  union { float f; unsigned u; } v; v.f = f;
  unsigned r = v.u + 0x7FFF + ((v.u >> 16) & 1);
  return (ushort)(r >> 16);
}
__device__ __forceinline__ float bf2f(ushort h) {
  union { unsigned u; float f; } v; v.u = ((unsigned)h) << 16;
  return v.f;
}

__device__ __forceinline__ float gelu_tanh(float x) {
  return 0.5f * x * (1.f + tanhf(0.7978845608028654f * (x + 0.044715f * x * x * x)));
}
__device__ __forceinline__ float gelu_fast(float x) {
  float u = 1.5957691216057308f * (x + 0.044715f * x * x * x);
  return x / (1.f + __expf(-u));
}

__device__ __forceinline__ void gl2lds16(const void* g, void* l) {
  __builtin_amdgcn_global_load_lds(
      (const __attribute__((address_space(1))) unsigned int*)g,
      (__attribute__((address_space(3))) unsigned int*)l, 16, 0, 0);
}

// ---------------------------------------------------------------------------
// Small weight convert+transpose (qkv & o-proj only, hi+lo).
// ---------------------------------------------------------------------------
__global__ __launch_bounds__(256) void wconv_kernel(
    const float* __restrict__ wq, const float* __restrict__ wo,
    ushort* __restrict__ wqT, ushort* __restrict__ wqTl,
    ushort* __restrict__ woT, ushort* __restrict__ woTl) {
  __shared__ __align__(16) ushort th[64 * 64];
  __shared__ __align__(16) ushort tl[64 * 64];
  int z = blockIdx.z, t = threadIdx.x;
  const float* src; ushort* dh; ushort* dl; int R, C, r0, c0;
  if (z == 0) {
    src = wq; dh = wqT; dl = wqTl;
    R = DIM; C = 3 * DIM; r0 = blockIdx.y * 64; c0 = blockIdx.x * 64;
  } else {
    if (blockIdx.x >= 16) return;
    src = wo; dh = woT; dl = woTl;
    R = DIM; C = DIM; r0 = blockIdx.y * 64; c0 = blockIdx.x * 64;
  }
  int ry = (t >> 4) * 4;
  int cx = (t & 15) * 4;
  f32x4 v[4];
#pragma unroll
  for (int j = 0; j < 4; j++)
    v[j] = *(const f32x4*)&src[(size_t)(r0 + ry + j) * C + c0 + cx];
#pragma unroll
  for (int i = 0; i < 4; i++) {
    int trow = cx + i;
    int o = trow * 64 + (((ry >> 3) ^ (trow & 7)) << 3) + (ry & 7);
    ushort uh[4], ul[4];
#pragma unroll
    for (int j = 0; j < 4; j++) {
      float f = v[j][i];
      ushort hh = f2bf(f);
      uh[j] = hh;
      ul[j] = f2bf(f - bf2f(hh));
    }
    *(s16x4*)&th[o] = *(const s16x4*)uh;
    *(s16x4*)&tl[o] = *(const s16x4*)ul;
  }
  __syncthreads();
  int tr = t >> 2, tc = (t & 3) * 16;
  int b0 = (tc >> 3) ^ (tr & 7);
  int b1 = ((tc >> 3) + 1) ^ (tr & 7);
  size_t dbase = (size_t)(c0 + tr) * R + r0 + tc;
  short8 u0 = *(const short8*)&th[tr * 64 + b0 * 8];
  short8 u1 = *(const short8*)&th[tr * 64 + b1 * 8];
  *(short8*)&dh[dbase] = u0;
  *(short8*)&dh[dbase + 8] = u1;
  short8 l0 = *(const short8*)&tl[tr * 64 + b0 * 8];
  short8 l1 = *(const short8*)&tl[tr * 64 + b1 * 8];
  *(short8*)&dl[dbase] = l0;
  *(short8*)&dl[dbase + 8] = l1;
}

// ---------------- fp32 -> bf16 hi/lo split (vectorized) ----------------
__global__ __launch_bounds__(256) void bfsplit_kernel(const float* __restrict__ in,
                                                      ushort* __restrict__ oh,
                                                      ushort* __restrict__ ol) {
  int i = (blockIdx.x * 256 + threadIdx.x) * 4;
  f32x4 v = *(const f32x4*)&in[i];
  ushort h[4], l[4];
#pragma unroll
  for (int j = 0; j < 4; j++) { h[j] = f2bf(v[j]); l[j] = f2bf(v[j] - bf2f(h[j])); }
  *(s16x4*)&oh[i] = *(const s16x4*)h;
  *(s16x4*)&ol[i] = *(const s16x4*)l;
}

// ---------------------------------------------------------------------------
// Fused expert GEMM (r11 structure, 128x128, depth-2 register prefetch).
// EPI 1: +bias +gelu -> bf16.  EPI 3: raw fp32 partial (+ ks*2048*N).
// ---------------------------------------------------------------------------
#define MM_FEXP_LOAD(ra0v, ra1v, rb0v, rb1v, rb2v, rb3v, T)            \
  { int _ko = (T) * 32;                                                \
    ra0v = *(const short8*)(aG[0] + _ko);                              \
    ra1v = *(const short8*)(aG[1] + _ko);                              \
    rb0v = *(const f32x4*)(bG + (size_t)(_ko + 0) * N);                \
    rb1v = *(const f32x4*)(bG + (size_t)(_ko + 1) * N);                \
    rb2v = *(const f32x4*)(bG + (size_t)(_ko + 2) * N);                \
    rb3v = *(const f32x4*)(bG + (size_t)(_ko + 3) * N); }

#define MM_FEXP_STAGE(buf, ra0v, ra1v, rb0v, rb1v, rb2v, rb3v)         \
  { *(short8*)&As[buf][aw[0]] = ra0v;                                  \
    *(short8*)&As[buf][aw[1]] = ra1v;                                  \
    _Pragma("unroll")                                                  \
    for (int i = 0; i < 4; i++) {                                      \
      ushort u[4];                                                     \
      u[0] = f2bf(rb0v[i]); u[1] = f2bf(rb1v[i]);                      \
      u[2] = f2bf(rb2v[i]); u[3] = f2bf(rb3v[i]);                      \
      *(s16x4*)&Bs[buf][(nb * 4 + i) * 40 + bslot * 4] = *(const s16x4*)u; } }

#define MM_FEXP_MFMA(buf)                                              \
  { short8 af[4], bf[4];                                               \
    _Pragma("unroll")                                                  \
    for (int mi = 0; mi < 4; mi++) af[mi] = *(const short8*)&As[buf][aro[mi]]; \
    _Pragma("unroll")                                                  \
    for (int ni = 0; ni < 4; ni++) bf[ni] = *(const short8*)&Bs[buf][bro[ni]]; \
    _Pragma("unroll")                                                  \
    for (int mi = 0; mi < 4; mi++)                                     \
      _Pragma("unroll")                                                \
      for (int ni = 0; ni < 4; ni++)                                   \
        acc[mi][ni] = __builtin_amdgcn_mfma_f32_16x16x32_bf16(af[mi], bf[ni], acc[mi][ni], 0, 0, 0); }

template <int EPI, int KSPLIT>
__global__ __launch_bounds__(256) void mm_fexp(
    const ushort* __restrict__ A, const float* __restrict__ Bf,
    const float* __restrict__ bias, void* __restrict__ Cout,
    const int* __restrict__ tok, const int* __restrict__ offcnt,
    int N, int K)
{
  int zz = blockIdx.z;
  int e  = (KSPLIT > 1) ? (zz & (NE - 1)) : zz;
  int ks = (KSPLIT > 1) ? (zz >> 3) : 0;
  int off = offcnt[e], cnt = offcnt[NE + e];
  int m0 = blockIdx.y * 128;
  if (m0 >= cnt) return;
  int n0 = blockIdx.x * 128;
  const float* Bp = Bf + (size_t)e * K * N;
  const int Kc = K / KSPLIT, kbase = ks * Kc;

  __shared__ __align__(16) ushort As[2][128 * 32];
  __shared__ __align__(16) ushort Bs[2][128 * 40];

  int t = threadIdx.x, lane = t & 63, w = t >> 6, wr = w >> 1, wc = w & 1;

  const ushort* aG[2]; int aw[2];
#pragma unroll
  for (int c = 0; c < 2; c++) {
    int gid = w * 128 + c * 64 + lane;
    int m = gid >> 2, p = gid & 3;
    int kg = p ^ ((m >> 1) & 3);
    int mc = m0 + m; if (mc > cnt - 1) mc = cnt - 1;
    int arow = tok ? tok[off + mc] : (off + mc);
    aG[c] = A + (size_t)arow * K + kbase + kg * 8;
    aw[c] = gid * 8;
  }

  int kb = t >> 5, nb = t & 31;
  const float* bG = Bp + (size_t)(kbase + kb * 4) * N + n0 + nb * 4;
  int bslot = kb ^ ((nb & 3) << 1);

  int aro[4], bro[4];
#pragma unroll
  for (int mi = 0; mi < 4; mi++) {
    int m = wr * 64 + mi * 16 + (lane & 15);
    aro[mi] = (m * 4 + ((lane >> 4) ^ ((m >> 1) & 3))) * 8;
  }
#pragma unroll
  for (int ni = 0; ni < 4; ni++) {
    int n = wc * 64 + ni * 16 + (lane & 15);
    bro[ni] = n * 40 + ((((lane >> 4) * 2) ^ (((n >> 2) & 3) << 1))) * 4;
  }

  f32x4 acc[4][4] = {};
  const int nt = Kc / 32;

  short8 raA0, raA1, raB0, raB1;
  f32x4 rbA0, rbA1, rbA2, rbA3, rbB0, rbB1, rbB2, rbB3;
  MM_FEXP_LOAD(raA0, raA1, rbA0, rbA1, rbA2, rbA3, 0);
  MM_FEXP_LOAD(raB0, raB1, rbB0, rbB1, rbB2, rbB3, 1);

  for (int tt = 0; tt < nt; tt += 2) {
    MM_FEXP_STAGE(0, raA0, raA1, rbA0, rbA1, rbA2, rbA3);
    if (tt + 2 < nt) MM_FEXP_LOAD(raA0, raA1, rbA0, rbA1, rbA2, rbA3, tt + 2);
    asm volatile("s_waitcnt lgkmcnt(0)" ::: "memory");
    __builtin_amdgcn_sched_barrier(0);
    __builtin_amdgcn_s_barrier();
    MM_FEXP_MFMA(0);
    MM_FEXP_STAGE(1, raB0, raB1, rbB0, rbB1, rbB2, rbB3);
    if (tt + 3 < nt) MM_FEXP_LOAD(raB0, raB1, rbB0, rbB1, rbB2, rbB3, tt + 3);
    asm volatile("s_waitcnt lgkmcnt(0)" ::: "memory");
    __builtin_amdgcn_sched_barrier(0);
    __builtin_amdgcn_s_barrier();
    MM_FEXP_MFMA(1);
  }

  const float* biasp = (EPI == 3) ? nullptr : bias + (size_t)e * N;
  float* Cp = (float*)Cout + (size_t)ks * 2048 * N;
#pragma unroll
  for (int mi = 0; mi < 4; mi++) {
#pragma unroll
    for (int j = 0; j < 4; j++) {
      int grow = m0 + wr * 64 + mi * 16 + (lane >> 4) * 4 + j;
      if (grow >= cnt) continue;
      size_t rbase = (size_t)(off + grow) * N;
#pragma unroll
      for (int ni = 0; ni < 4; ni++) {
        int gcol = n0 + wc * 64 + ni * 16 + (lane & 15);
        float v = acc[mi][ni][j];
        if (EPI == 1) ((ushort*)Cout)[rbase + gcol] = f2bf(gelu_fast(v + biasp[gcol]));
        else          Cp[rbase + gcol] = v;
      }
    }
  }
}

#undef MM_FEXP_LOAD
#undef MM_FEXP_STAGE
#undef MM_FEXP_MFMA

// ---------------------------------------------------------------------------
// Split-precision GEMM (pre-router path).
// ---------------------------------------------------------------------------
__global__ __launch_bounds__(256) void mm_split(
    const ushort* __restrict__ Ah, const ushort* __restrict__ Al,
    const ushort* __restrict__ Bh, const ushort* __restrict__ Bl,
    float* __restrict__ C, int N, int K)
{
  int m0 = blockIdx.y * 128;
  int n0 = blockIdx.x * 128;

  __shared__ __align__(16) ushort Ahs[2][4096], Als[2][4096];
  __shared__ __align__(16) ushort Bhs[2][4096], Bls[2][4096];

  int t = threadIdx.x, lane = t & 63, w = t >> 6, wr = w >> 1, wc = w & 1;

  const ushort *aGh[2], *aGl[2], *bGh[2], *bGl[2];
  int lofs[2];
#pragma unroll
  for (int c = 0; c < 2; c++) {
    int gid = w * 128 + c * 64 + lane;
    int m = gid >> 2, p = gid & 3;
    int kg = p ^ ((m >> 1) & 3);
    aGh[c] = Ah + (size_t)(m0 + m) * K + kg * 8;
    aGl[c] = Al + (size_t)(m0 + m) * K + kg * 8;
    bGh[c] = Bh + (size_t)(n0 + m) * K + kg * 8;
    bGl[c] = Bl + (size_t)(n0 + m) * K + kg * 8;
    lofs[c] = (w * 128 + c * 64) * 8;
  }

  int aro[4], bro[4];
#pragma unroll
  for (int mi = 0; mi < 4; mi++) {
    int m = wr * 64 + mi * 16 + (lane & 15);
    aro[mi] = (m * 4 + ((lane >> 4) ^ ((m >> 1) & 3))) * 8;
  }
#pragma unroll
  for (int ni = 0; ni < 4; ni++) {
    int n = wc * 64 + ni * 16 + (lane & 15);
    bro[ni] = (n * 4 + ((lane >> 4) ^ ((n >> 1) & 3))) * 8;
  }

  f32x4 acc[4][4] = {};
  const int nt = K / 32;

#pragma unroll
  for (int c = 0; c < 2; c++) {
    gl2lds16(aGh[c], &Ahs[0][lofs[c]]); gl2lds16(aGl[c], &Als[0][lofs[c]]);
    gl2lds16(bGh[c], &Bhs[0][lofs[c]]); gl2lds16(bGl[c], &Bls[0][lofs[c]]);
  }
  if (nt > 1) {
#pragma unroll
    for (int c = 0; c < 2; c++) {
      gl2lds16(aGh[c] + 32, &Ahs[1][lofs[c]]); gl2lds16(aGl[c] + 32, &Als[1][lofs[c]]);
      gl2lds16(bGh[c] + 32, &Bhs[1][lofs[c]]); gl2lds16(bGl[c] + 32, &Bls[1][lofs[c]]);
    }
  }

  for (int tt = 0; tt < nt; tt++) {
    if (tt + 1 < nt) WAIT_VM(8); else WAIT_VM(0);
    __builtin_amdgcn_s_barrier();
    int b = tt & 1;
    short8 ah[4], al_[4], bh[4], bl_[4];
#pragma unroll
    for (int mi = 0; mi < 4; mi++) {
      ah[mi] = *(const short8*)&Ahs[b][aro[mi]];
      al_[mi] = *(const short8*)&Als[b][aro[mi]];
    }
#pragma unroll
    for (int ni = 0; ni < 4; ni++) {
      bh[ni] = *(const short8*)&Bhs[b][bro[ni]];
      bl_[ni] = *(const short8*)&Bls[b][bro[ni]];
    }
#pragma unroll
    for (int mi = 0; mi < 4; mi++)
#pragma unroll
      for (int ni = 0; ni < 4; ni++) {
        acc[mi][ni] = __builtin_amdgcn_mfma_f32_16x16x32_bf16(al_[mi], bh[ni], acc[mi][ni], 0, 0, 0);
        acc[mi][ni] = __builtin_amdgcn_mfma_f32_16x16x32_bf16(ah[mi], bl_[ni], acc[mi][ni], 0, 0, 0);
        acc[mi][ni] = __builtin_amdgcn_mfma_f32_16x16x32_bf16(ah[mi], bh[ni], acc[mi][ni], 0, 0, 0);
      }
    asm volatile("s_waitcnt lgkmcnt(0)" ::: "memory");
    __builtin_amdgcn_sched_barrier(0);
    __builtin_amdgcn_s_barrier();
    if (tt + 2 < nt) {
      int ko = (tt + 2) * 32;
#pragma unroll
      for (int c = 0; c < 2; c++) {
        gl2lds16(aGh[c] + ko, &Ahs[b][lofs[c]]); gl2lds16(aGl[c] + ko, &Als[b][lofs[c]]);
        gl2lds16(bGh[c] + ko, &Bhs[b][lofs[c]]); gl2lds16(bGl[c] + ko, &Bls[b][lofs[c]]);
      }
    }
  }

#pragma unroll
  for (int mi = 0; mi < 4; mi++)
#pragma unroll
    for (int j = 0; j < 4; j++) {
      int grow = m0 + wr * 64 + mi * 16 + (lane >> 4) * 4 + j;
      size_t rbase = (size_t)grow * N;
#pragma unroll
      for (int ni = 0; ni < 4; ni++) {
        int gcol = n0 + wc * 64 + ni * 16 + (lane & 15);
        C[rbase + gcol] = acc[mi][ni][j];
      }
    }
}

// ---------------------------------------------------------------------------
// bf16-MFMA GEMM with in-loop conversion (fallback path only).
// ---------------------------------------------------------------------------
template <int EPI, int SPLIT>
__global__ __launch_bounds__(256) void mm_bf16(
    const float* __restrict__ A, const float* __restrict__ B,
    const float* __restrict__ bias, float* __restrict__ C,
    const int* __restrict__ tok, const int* __restrict__ offcnt,
    int M, int N, int K)
{
  int e = blockIdx.z;
  int off = 0, cnt = M;
  if (offcnt) { off = offcnt[e]; cnt = offcnt[NE + e]; }
  int m0 = blockIdx.y * 128;
  if (m0 >= cnt) return;
  const float* Bp = B + (size_t)e * K * N;
  const float* biasp = (EPI == 0) ? nullptr : bias + (size_t)e * N;
  int n0 = blockIdx.x * 128;

  __shared__ __align__(16) ushort As[(SPLIT + 1) * 128 * 32];
  __shared__ __align__(16) ushort Bs[(SPLIT + 1) * 128 * 32];

  int t = threadIdx.x;
  int lane = t & 63;
  int w = t >> 6, wr = w >> 1, wc = w & 1;

  const float* aptr[2];
  int aws[2];
  for (int i = 0; i < 2; i++) {
    int mr = i * 64 + (t >> 2);
    int mc = m0 + mr; if (mc > cnt - 1) mc = cnt - 1;
    int arow = tok ? tok[off + mc] : (off + mc);
    aptr[i] = A + (size_t)arow * K + (t & 3) * 8;
    aws[i] = mr * 32 + (t & 3) * 8;
  }

  int bn = t >> 1, bkh = (t & 1) * 16;
  const float* bptr = Bp + (size_t)bkh * N + n0 + bn;
  int bws0 = bn * 32 + 8 * (((bkh >> 3) + 0) ^ (bn & 3));
  int bws1 = bn * 32 + 8 * (((bkh >> 3) + 1) ^ (bn & 3));

  int aro[4], bro[4];
#pragma unroll
  for (int mi = 0; mi < 4; mi++)
    aro[mi] = (wr * 64 + mi * 16 + (lane & 15)) * 32 + (lane >> 4) * 8;
#pragma unroll
  for (int ni = 0; ni < 4; ni++) {
    int n = wc * 64 + ni * 16 + (lane & 15);
    bro[ni] = n * 32 + 8 * ((lane >> 4) ^ (n & 3));
  }

  f32x4 acc[4][4] = {};

  for (int k0 = 0; k0 < K; k0 += 32) {
#pragma unroll
    for (int i = 0; i < 2; i++) {
      f32x4 v0 = *(const f32x4*)(aptr[i] + k0);
      f32x4 v1 = *(const f32x4*)(aptr[i] + k0 + 4);
      ushort uh[8], ul[8];
#pragma unroll
      for (int j = 0; j < 4; j++) {
        float f0 = v0[j], f1 = v1[j];
        ushort h0 = f2bf(f0), h1 = f2bf(f1);
        uh[j] = h0; uh[4 + j] = h1;
        if (SPLIT) { ul[j] = f2bf(f0 - bf2f(h0)); ul[4 + j] = f2bf(f1 - bf2f(h1)); }
      }
      *(short8*)&As[aws[i]] = *(const short8*)uh;
      if (SPLIT) *(short8*)&As[4096 + aws[i]] = *(const short8*)ul;
    }
    {
      const float* bp = bptr + (size_t)k0 * N;
      ushort uh[16], ul[16];
#pragma unroll
      for (int i = 0; i < 16; i++) {
        float f = bp[(size_t)i * N];
        ushort h = f2bf(f);
        uh[i] = h;
        if (SPLIT) ul[i] = f2bf(f - bf2f(h));
      }
      *(short8*)&Bs[bws0] = *(const short8*)&uh[0];
      *(short8*)&Bs[bws1] = *(const short8*)&uh[8];
      if (SPLIT) {
        *(short8*)&Bs[4096 + bws0] = *(const short8*)&ul[0];
        *(short8*)&Bs[4096 + bws1] = *(const short8*)&ul[8];
      }
    }
    __syncthreads();
    short8 afh[4], bfh[4], afl[4], bfl[4];
#pragma unroll
    for (int mi = 0; mi < 4; mi++) {
      afh[mi] = *(const short8*)&As[aro[mi]];
      if (SPLIT) afl[mi] = *(const short8*)&As[4096 + aro[mi]];
    }
#pragma unroll
    for (int ni = 0; ni < 4; ni++) {
      bfh[ni] = *(const short8*)&Bs[bro[ni]];
      if (SPLIT) bfl[ni] = *(const short8*)&Bs[4096 + bro[ni]];
    }
#pragma unroll
    for (int mi = 0; mi < 4; mi++)
#pragma unroll
      for (int ni = 0; ni < 4; ni++) {
        if (SPLIT) {
          acc[mi][ni] = __builtin_amdgcn_mfma_f32_16x16x32_bf16(afl[mi], bfh[ni], acc[mi][ni], 0, 0, 0);
          acc[mi][ni] = __builtin_amdgcn_mfma_f32_16x16x32_bf16(afh[mi], bfl[ni], acc[mi][ni], 0, 0, 0);
        }
        acc[mi][ni] = __builtin_amdgcn_mfma_f32_16x16x32_bf16(afh[mi], bfh[ni], acc[mi][ni], 0, 0, 0);
      }
    __syncthreads();
  }

#pragma unroll
  for (int mi = 0; mi < 4; mi++) {
#pragma unroll
    for (int j = 0; j < 4; j++) {
      int grow = m0 + wr * 64 + mi * 16 + (lane >> 4) * 4 + j;
      if (grow >= cnt) continue;
      size_t rbase = (size_t)(off + grow) * N;
#pragma unroll
      for (int ni = 0; ni < 4; ni++) {
        int gcol = n0 + wc * 64 + ni * 16 + (lane & 15);
        float v = acc[mi][ni][j];
        if (EPI >= 1) v += biasp[gcol];
        if (EPI == 1) v = gelu_tanh(v);
        C[rbase + gcol] = v;
      }
    }
  }
}

// ---------------------------------------------------------------------------
// MFMA flash attention, split-bf16, KV-chunked (2 chunks per q-block).
// Grid (8 qb, 2 ch, 16 heads) = 256 blocks; each chunk does (qb+1) tiles.
// Partials: opart[ch][row][dim] unnormalized O; ml[ch][head][row]{m,l}.
// Sentinel -1e30 (not -inf) so fully-masked chunk rows stay finite and get
// weight exp(m-M)=0 at combine.
// ---------------------------------------------------------------------------
__device__ __forceinline__ int vidx(int d, int key) {
  return d * 64 + ((((key >> 3) ^ (d & 7)) << 3) | (key & 7));
}

__global__ __launch_bounds__(256, 1) void attn_mfma(const float* __restrict__ qkv,
                                                    float* __restrict__ opart,
                                                    float* __restrict__ ml) {
  const int qb = blockIdx.x;
  const int ch = blockIdx.y;
  const int head = blockIdx.z;
  const int q0 = qb * 128;
  const int t = threadIdx.x;
  const int lane = t & 63, w = t >> 6;
  const int g = lane >> 4, l4 = lane & 15;

  __shared__ __align__(16) ushort Kh[64 * 64], Kl[64 * 64];
  __shared__ __align__(16) ushort Vh[64 * 64], Vl[64 * 64];
  __shared__ __align__(16) ushort Ph[4][32 * 72], Pl[4][32 * 72];

  short8 qh[2][2], ql[2][2];
#pragma unroll
  for (int mi = 0; mi < 2; mi++)
#pragma unroll
    for (int ks = 0; ks < 2; ks++) {
      int row = q0 + w * 32 + mi * 16 + l4;
      const float* qp = qkv + (size_t)row * 3072 + head * 64 + ks * 32 + g * 8;
      f32x4 a = *(const f32x4*)qp;
      f32x4 b4 = *(const f32x4*)(qp + 4);
      ushort uh[8], ul_[8];
#pragma unroll
      for (int j = 0; j < 4; j++) {
        ushort h0 = f2bf(a[j]), h1 = f2bf(b4[j]);
        uh[j] = h0; uh[4 + j] = h1;
        ul_[j] = f2bf(a[j] - bf2f(h0)); ul_[4 + j] = f2bf(b4[j] - bf2f(h1));
      }
      qh[mi][ks] = *(const short8*)uh;
      ql[mi][ks] = *(const short8*)ul_;
    }

  float m_s[2][4], l_s[2][4];
  f32x4 O[2][4] = {};
#pragma unroll
  for (int mi = 0; mi < 2; mi++)
#pragma unroll
    for (int j = 0; j < 4; j++) { m_s[mi][j] = -1e30f; l_s[mi][j] = 0.f; }

  const int kt_beg = ch ? (qb + 1) : 0;
  const int kt_end = ch ? 2 * (qb + 1) : (qb + 1);
  for (int kt = kt_beg; kt < kt_end; kt++) {
    const int kv0 = kt * 64;
    __syncthreads();
    {
      int key = t >> 2;
      int dblk = (t & 3) * 16;
      const float* kp = qkv + (size_t)(kv0 + key) * 3072 + 1024 + head * 64 + dblk;
      const float* vp = kp + 1024;
      f32x4 k0 = *(const f32x4*)kp, k1 = *(const f32x4*)(kp + 4),
            k2 = *(const f32x4*)(kp + 8), k3 = *(const f32x4*)(kp + 12);
      f32x4 v0 = *(const f32x4*)vp, v1 = *(const f32x4*)(vp + 4),
            v2 = *(const f32x4*)(vp + 8), v3 = *(const f32x4*)(vp + 12);
      float kf[16] = {k0[0],k0[1],k0[2],k0[3], k1[0],k1[1],k1[2],k1[3],
                      k2[0],k2[1],k2[2],k2[3], k3[0],k3[1],k3[2],k3[3]};
      float vf[16] = {v0[0],v0[1],v0[2],v0[3], v1[0],v1[1],v1[2],v1[3],
                      v2[0],v2[1],v2[2],v2[3], v3[0],v3[1],v3[2],v3[3]};
#pragma unroll
      for (int half = 0; half < 2; half++) {
        int d8 = (dblk >> 3) + half;
        int idx = key * 64 + ((d8 ^ (key & 7)) << 3);
        ushort uh[8], ul_[8];
#pragma unroll
        for (int j = 0; j < 8; j++) {
          float f = kf[half * 8 + j];
          ushort h = f2bf(f);
          uh[j] = h; ul_[j] = f2bf(f - bf2f(h));
        }
        *(short8*)&Kh[idx] = *(const short8*)uh;
        *(short8*)&Kl[idx] = *(const short8*)ul_;
      }
#pragma unroll
      for (int i = 0; i < 16; i++) {
        int d = dblk + i;
        int idx = vidx(d, key);
        float f = vf[i];
        ushort h = f2bf(f);
        Vh[idx] = h; Vl[idx] = f2bf(f - bf2f(h));
      }
    }
    __syncthreads();

    if (kv0 <= q0 + w * 32 + 31) {
      f32x4 S[2][4] = {};
#pragma unroll
      for (int ks = 0; ks < 2; ks++) {
        short8 kbh[4], kbl[4];
#pragma unroll
        for (int ni = 0; ni < 4; ni++) {
          int key = ni * 16 + l4;
          int d8 = ks * 4 + g;
          int idx = key * 64 + ((d8 ^ (key & 7)) << 3);
          kbh[ni] = *(const short8*)&Kh[idx];
          kbl[ni] = *(const short8*)&Kl[idx];
        }
#pragma unroll
        for (int mi = 0; mi < 2; mi++)
#pragma unroll
          for (int ni = 0; ni < 4; ni++) {
            S[mi][ni] = __builtin_amdgcn_mfma_f32_16x16x32_bf16(ql[mi][ks], kbh[ni], S[mi][ni], 0, 0, 0);
            S[mi][ni] = __builtin_amdgcn_mfma_f32_16x16x32_bf16(qh[mi][ks], kbl[ni], S[mi][ni], 0, 0, 0);
            S[mi][ni] = __builtin_amdgcn_mfma_f32_16x16x32_bf16(qh[mi][ks], kbh[ni], S[mi][ni], 0, 0, 0);
          }
      }
#pragma unroll
      for (int mi = 0; mi < 2; mi++) {
        int rowb = q0 + w * 32 + mi * 16 + g * 4;
        float mx[4] = {-1e30f, -1e30f, -1e30f, -1e30f};
#pragma unroll
        for (int ni = 0; ni < 4; ni++) {
          int col = kv0 + ni * 16 + l4;
#pragma unroll
          for (int j = 0; j < 4; j++) {
            float s = S[mi][ni][j] * 0.125f;
            if (col > rowb + j) s = -1e30f;
            S[mi][ni][j] = s;
            mx[j] = fmaxf(mx[j], s);
          }
        }
#pragma unroll
        for (int j = 0; j < 4; j++) {
#pragma unroll
          for (int msk = 8; msk; msk >>= 1) mx[j] = fmaxf(mx[j], __shfl_xor(mx[j], msk));
          float mn = fmaxf(m_s[mi][j], mx[j]);
          float sc = __expf(m_s[mi][j] - mn);
          m_s[mi][j] = mn;
          l_s[mi][j] *= sc;
#pragma unroll
          for (int df = 0; df < 4; df++) O[mi][df][j] *= sc;
        }
        float ps[4] = {0.f, 0.f, 0.f, 0.f};
#pragma unroll
        for (int ni = 0; ni < 4; ni++)
#pragma unroll
          for (int j = 0; j < 4; j++) {
            float p = __expf(S[mi][ni][j] - m_s[mi][j]);
            ps[j] += p;
            int rl = mi * 16 + g * 4 + j, cl = ni * 16 + l4;
            ushort h = f2bf(p);
            Ph[w][rl * 72 + cl] = h;
            Pl[w][rl * 72 + cl] = f2bf(p - bf2f(h));
          }
#pragma unroll
        for (int j = 0; j < 4; j++) {
#pragma unroll
          for (int msk = 8; msk; msk >>= 1) ps[j] += __shfl_xor(ps[j], msk);
          l_s[mi][j] += ps[j];
        }
      }
      asm volatile("s_waitcnt lgkmcnt(0)" ::: "memory");
      __builtin_amdgcn_sched_barrier(0);
#pragma unroll
      for (int ks = 0; ks < 2; ks++) {
        short8 pah[2], pal[2], vbh[4], vbl[4];
#pragma unroll
        for (int mi = 0; mi < 2; mi++) {
          int idx = (mi * 16 + l4) * 72 + ks * 32 + g * 8;
          pah[mi] = *(const short8*)&Ph[w][idx];
          pal[mi] = *(const short8*)&Pl[w][idx];
        }
#pragma unroll
        for (int df = 0; df < 4; df++) {
          int d = df * 16 + l4;
          int k8 = ks * 4 + g;
          int idx = d * 64 + ((k8 ^ (d & 7)) << 3);
          vbh[df] = *(const short8*)&Vh[idx];
          vbl[df] = *(const short8*)&Vl[idx];
        }
#pragma unroll
        for (int mi = 0; mi < 2; mi++)
#pragma unroll
          for (int df = 0; df < 4; df++) {
            O[mi][df] = __builtin_amdgcn_mfma_f32_16x16x32_bf16(pal[mi], vbh[df], O[mi][df], 0, 0, 0);
            O[mi][df] = __builtin_amdgcn_mfma_f32_16x16x32_bf16(pah[mi], vbl[df], O[mi][df], 0, 0, 0);
            O[mi][df] = __builtin_amdgcn_mfma_f32_16x16x32_bf16(pah[mi], vbh[df], O[mi][df], 0, 0, 0);
          }
      }
    }
  }

  // ---- write partials ----
#pragma unroll
  for (int mi = 0; mi < 2; mi++)
#pragma unroll
    for (int j = 0; j < 4; j++) {
      int row = q0 + w * 32 + mi * 16 + g * 4 + j;
      if (l4 == 0) {
        float* mlp = ml + (((size_t)ch * NH + head) * SEQ + row) * 2;
        mlp[0] = m_s[mi][j];
        mlp[1] = l_s[mi][j];
      }
#pragma unroll
      for (int df = 0; df < 4; df++)
        opart[(size_t)ch * (SEQ * DIM) + (size_t)row * DIM + head * 64 + df * 16 + l4] =
            O[mi][df][j];
    }
}

// ---------------- combine 2 KV-chunk partials -> attn_o ----------------
__global__ __launch_bounds__(256) void attn_combine(const float* __restrict__ opart,
                                                    const float* __restrict__ ml,
                                                    float* __restrict__ o) {
  int row = blockIdx.x, t = threadIdx.x;
  int d0 = t * 4;
  int head = d0 >> 6;
  const float* p0 = ml + (((size_t)0 * NH + head) * SEQ + row) * 2;
  const float* p1 = ml + (((size_t)1 * NH + head) * SEQ + row) * 2;
  float m0 = p0[0], l0 = p0[1], m1 = p1[0], l1 = p1[1];
  float M = fmaxf(m0, m1);
  float w0 = __expf(m0 - M), w1 = __expf(m1 - M);
  float inv = 1.f / (l0 * w0 + l1 * w1);
  f32x4 O0 = *(const f32x4*)&opart[(size_t)row * DIM + d0];
  f32x4 O1 = *(const f32x4*)&opart[(size_t)(SEQ * DIM) + (size_t)row * DIM + d0];
  f32x4 r;
#pragma unroll
  for (int j = 0; j < 4; j++) r[j] = (O0[j] * w0 + O1[j] * w1) * inv;
  *(f32x4*)&o[(size_t)row * DIM + d0] = r;
}

// ---------------- block reduce helper ----------------
__device__ float block_reduce_256(float v, float* red, int t) {
  red[t] = v; __syncthreads();
  for (int st = 128; st > 0; st >>= 1) {
    if (t < st) red[t] += red[t + st];
    __syncthreads();
  }
  float r = red[0];
  __syncthreads();
  return r;
}

// ---------------- h = LN(x + r) * g + b  (+ optional bf16 copy) ----------------
__global__ __launch_bounds__(256) void addln_kernel(const float* __restrict__ x,
                                                    const float* __restrict__ r,
                                                    const float* __restrict__ g,
                                                    const float* __restrict__ b,
                                                    float* __restrict__ out,
                                                    ushort* __restrict__ outb) {
  __shared__ float red[256];
  int row = blockIdx.x, t = threadIdx.x;
  float vals[4];
  float s = 0.f;
  for (int i = 0; i < 4; i++) {
    int d = t + i * 256;
    vals[i] = x[(size_t)row * DIM + d] + r[(size_t)row * DIM + d];
    s += vals[i];
  }
  float mean = block_reduce_256(s, red, t) * (1.f / DIM);
  float vs = 0.f;
  for (int i = 0; i < 4; i++) { float d = vals[i] - mean; vs += d * d; }
  float var = block_reduce_256(vs, red, t) * (1.f / DIM);
  float inv = rsqrtf(var + 1e-5f);
  for (int i = 0; i < 4; i++) {
    int d = t + i * 256;
    float v = (vals[i] - mean) * inv * g[d] + b[d];
    out[(size_t)row * DIM + d] = v;
    if (outb) outb[(size_t)row * DIM + d] = f2bf(v);
  }
}

// ---------------- router ----------------
__global__ __launch_bounds__(256) void router_kernel(const float* __restrict__ h,
                                                     const float* __restrict__ wg,
                                                     int* __restrict__ topi,
                                                     float* __restrict__ topw) {
  __shared__ float red[NE][256];
  int tkn = blockIdx.x, t = threadIdx.x;
  float acc[NE] = {};
  for (int i = 0; i < 4; i++) {
    int d = t + i * 256;
    float hv = h[(size_t)tkn * DIM + d];
    const float* wr = wg + (size_t)d * NE;
    for (int e = 0; e < NE; e++) acc[e] += hv * wr[e];
  }
  for (int e = 0; e < NE; e++) red[e][t] = acc[e];
  __syncthreads();
  for (int st = 128; st > 0; st >>= 1) {
    if (t < st)
      for (int e = 0; e < NE; e++) red[e][t] += red[e][t + st];
    __syncthreads();
  }
  if (t == 0) {
    float l[NE];
    for (int e = 0; e < NE; e++) l[e] = red[e][0];
    int i0 = 0;
    for (int e = 1; e < NE; e++) if (l[e] > l[i0]) i0 = e;
    int i1 = -1;
    for (int e = 0; e < NE; e++) {
      if (e == i0) continue;
      if (i1 < 0 || l[e] > l[i1]) i1 = e;
    }
    float p1 = __expf(l[i1] - l[i0]);
    float inv = 1.f / (1.f + p1);
    topi[tkn * 2] = i0; topi[tkn * 2 + 1] = i1;
    topw[tkn * 2] = inv; topw[tkn * 2 + 1] = p1 * inv;
  }
}

// ---------------- deterministic per-expert compaction (1 block) ----------------
__global__ __launch_bounds__(1024) void compact_kernel(const int* __restrict__ topi,
                                                       int* __restrict__ tok,
                                                       int* __restrict__ assign_row,
                                                       int* __restrict__ offcnt) {
  __shared__ int scan[1024];
  __shared__ int sbase;
  int t = threadIdx.x;
  if (t == 0) sbase = 0;
  __syncthreads();
  for (int e = 0; e < NE; e++) {
    int which = -1;
    if (topi[t * 2] == e) which = 0;
    else if (topi[t * 2 + 1] == e) which = 1;
    scan[t] = (which >= 0) ? 1 : 0;
    __syncthreads();
    for (int s2 = 1; s2 < 1024; s2 <<= 1) {
      int add = (t >= s2) ? scan[t - s2] : 0;
      __syncthreads();
      scan[t] += add;
      __syncthreads();
    }
    int incl = scan[t];
    int total = scan[1023];
    int base = sbase;
    if (which >= 0) {
      int pos = base + incl - 1;
      tok[pos] = t;
      assign_row[t * 2 + which] = pos;
    }
    if (t == 0) { offcnt[e] = base; offcnt[NE + e] = total; }
    __syncthreads();
    if (t == 0) sbase = base + total;
    __syncthreads();
  }
}

// ---------------- final: out = LN(h + combine(moe)) ----------------
template <int KS>
__global__ __launch_bounds__(256) void final_ln_kernel(const float* __restrict__ h,
                                                       const float* __restrict__ y,
                                                       const int* __restrict__ assign_row,
                                                       const float* __restrict__ topw,
                                                       const int* __restrict__ topi,
                                                       const float* __restrict__ bb2,
                                                       const float* __restrict__ g,
                                                       const float* __restrict__ b,
                                                       float* __restrict__ out) {
  __shared__ float red[256];
  int row = blockIdx.x, t = threadIdx.x;
  int r0 = assign_row[row * 2], r1 = assign_row[row * 2 + 1];
  float w0 = topw[row * 2], w1 = topw[row * 2 + 1];
  float vals[4];
  float s = 0.f;
  for (int i = 0; i < 4; i++) {
    int d = t + i * 256;
    float acc0 = 0.f, acc1 = 0.f;
#pragma unroll
    for (int p = 0; p < KS; p++) {
      acc0 += y[(size_t)p * 2048 * DIM + (size_t)r0 * DIM + d];
      acc1 += y[(size_t)p * 2048 * DIM + (size_t)r1 * DIM + d];
    }
    float v = h[(size_t)row * DIM + d] + w0 * acc0 + w1 * acc1;
    if (KS > 1) {
      int e0 = topi[row * 2], e1 = topi[row * 2 + 1];
      v += w0 * bb2[e0 * DIM + d] + w1 * bb2[e1 * DIM + d];
    }
    vals[i] = v;
    s += v;
  }
  float mean = block_reduce_256(s, red, t) * (1.f / DIM);
  float vs = 0.f;
  for (int i = 0; i < 4; i++) { float d = vals[i] - mean; vs += d * d; }
  float var = block_reduce_256(vs, red, t) * (1.f / DIM);
  float inv = rsqrtf(var + 1e-5f);
  for (int i = 0; i < 4; i++) {
    int d = t + i * 256;
    out[(size_t)row * DIM + d] = (vals[i] - mean) * inv * g[d] + b[d];
  }
}

extern "C" void kernel_launch(void* const* d_in, const int* in_sizes, int n_in,
                              void* d_out, int out_size, void* d_ws, size_t ws_size,
                              hipStream_t stream) {
  const float* x     = (const float*)d_in[0];
  const float* w_qkv = (const float*)d_in[1];
  const float* w_o   = (const float*)d_in[2];
  const float* g1    = (const float*)d_in[3];
  const float* b1    = (const float*)d_in[4];
  const float* wg    = (const float*)d_in[5];
  const float* w1    = (const float*)d_in[6];
  const float* bb1   = (const float*)d_in[7];
  const float* w2    = (const float*)d_in[8];
  const float* bb2   = (const float*)d_in[9];
  const float* g2    = (const float*)d_in[10];
  const float* b2    = (const float*)d_in[11];
  float* out = (float*)d_out;
  float* ws = (float*)d_ws;

  const bool fast = ws_size >= (size_t)46671872 * 4;

  if (fast) {
    float* qkv    = ws;                       // 3,145,728 f
    float* attn_o = ws + 3145728;             // 1,048,576 f
    float* oproj  = ws + 4194304;             // 1,048,576 f
    float* h      = ws + 5242880;             // 1,048,576 f
    float* ybuf   = ws + 6291456;             // 2,097,152 f (xh/xl/oh/ol aliases)
    float* topw   = ws + 8388608;             // 2,048 f
    int*   ibase  = (int*)(ws + 8390656);     // 8,192 ints
    int* topi       = ibase;
    int* tok        = ibase + 2048;
    int* assign_row = ibase + 4096;
    int* offcnt     = ibase + 6144;
    ushort* hb  = (ushort*)(ws + 8398848);    // 1,048,576 us
    ushort* h1b = (ushort*)(ws + 8923136);    // 8,388,608 us
    ushort* wqT  = (ushort*)(ws + 13117440);  // 3,145,728 us
    ushort* wqTl = wqT + 3145728;             // 3,145,728 us
    ushort* woT  = wqT + 6291456;             // 1,048,576 us
    ushort* woTl = wqT + 7340032;             // 1,048,576 us  (ends at f 17,311,744)
    float* ypart = ws + 17311744;             // 8,388,608 f (32 MB K-split partials)
    ushort* xh = (ushort*)ybuf;               // activation split aliases
    ushort* xl = xh + 1048576;
    ushort* oh = xh + 2097152;
    ushort* ol = xh + 3145728;
    // attn partials alias the ypart region (dead until step 8)
    float* opart = ypart;                     // 2 x 1,048,576 f
    float* mlbuf = ypart + 2097152;           // 65,536 f

    // 0. small weight convert/transpose (qkv & o-proj, hi+lo)
    wconv_kernel<<<dim3(48, 16, 2), 256, 0, stream>>>(w_qkv, w_o,
                                                      wqT, wqTl, woT, woTl);
    // 0b. split x
    bfsplit_kernel<<<dim3(SEQ * DIM / 1024), 256, 0, stream>>>(x, xh, xl);
    // 1. qkv = x @ w_qkv  (pipelined split GEMM)
    mm_split<<<dim3(24, 8), 256, 0, stream>>>(xh, xl, wqT, wqTl, qkv, 3 * DIM, DIM);
    // 2. attention (KV-chunked: 256 balanced blocks) + combine
    attn_mfma<<<dim3(8, 2, NH), 256, 0, stream>>>(qkv, opart, mlbuf);
    attn_combine<<<dim3(SEQ), 256, 0, stream>>>(opart, mlbuf, attn_o);
    // 2b. split attn_o
    bfsplit_kernel<<<dim3(SEQ * DIM / 1024), 256, 0, stream>>>(attn_o, oh, ol);
    // 3. oproj = attn_o @ w_o
    mm_split<<<dim3(8, 8), 256, 0, stream>>>(oh, ol, woT, woTl, oproj, DIM, DIM);
    // 4. h = LN(x + oproj), + bf16 copy
    addln_kernel<<<dim3(SEQ), 256, 0, stream>>>(x, oproj, g1, b1, h, hb);
    // 5. router
    router_kernel<<<dim3(SEQ), 256, 0, stream>>>(h, wg, topi, topw);
    // 6. compaction
    compact_kernel<<<dim3(1), 1024, 0, stream>>>(topi, tok, assign_row, offcnt);
    // 7. expert up+gelu -> bf16 (fused fp32-w1 conversion, depth-2 prefetch)
    mm_fexp<1, 1><<<dim3(FF / 128, 8, NE), 256, 0, stream>>>(hb, w1, bb1, (void*)h1b,
                                                             tok, offcnt, FF, DIM);
    // 8. expert down, K-split 4 -> fp32 partials (overwrites opart/ml; dead)
    mm_fexp<3, 4><<<dim3(DIM / 128, 8, NE * 4), 256, 0, stream>>>(h1b, w2, nullptr,
                                                                  (void*)ypart,
                                                                  nullptr, offcnt, DIM, FF);
    // 9. combine partials + bb2 + residual + LN
    final_ln_kernel<4><<<dim3(SEQ), 256, 0, stream>>>(h, ypart, assign_row, topw,
                                                      topi, bb2, g2, b2, out);
  } else {
    float* qkv    = ws;
    float* attn_o = ws + 3145728;
    float* oproj  = ws + 4194304;
    float* h      = ws + 5242880;
    float* h1     = ws + 6291456;              // 8,388,608 f
    float* ybuf   = ws + 14680064;
    float* topw   = ws + 16777216;
    int*   ibase  = (int*)(ws + 16779264);
    int* topi       = ibase;
    int* tok        = ibase + 2048;
    int* assign_row = ibase + 4096;
    int* offcnt     = ibase + 6144;
    float* opart = h1;                         // alias (dead until step 7)
    float* mlbuf = h1 + 2097152;

    mm_bf16<0, 1><<<dim3(24, 8, 1), 256, 0, stream>>>(x, w_qkv, nullptr, qkv,
                                                      nullptr, nullptr, SEQ, 3 * DIM, DIM);
    attn_mfma<<<dim3(8, 2, NH), 256, 0, stream>>>(qkv, opart, mlbuf);
    attn_combine<<<dim3(SEQ), 256, 0, stream>>>(opart, mlbuf, attn_o);
    mm_bf16<0, 1><<<dim3(8, 8, 1), 256, 0, stream>>>(attn_o, w_o, nullptr, oproj,
                                                     nullptr, nullptr, SEQ, DIM, DIM);
    addln_kernel<<<dim3(SEQ), 256, 0, stream>>>(x, oproj, g1, b1, h, nullptr);
    router_kernel<<<dim3(SEQ), 256, 0, stream>>>(h, wg, topi, topw);
    compact_kernel<<<dim3(1), 1024, 0, stream>>>(topi, tok, assign_row, offcnt);
    mm_bf16<1, 0><<<dim3(32, 8, NE), 256, 0, stream>>>(h, w1, bb1, h1,
                                                       tok, offcnt, SEQ, FF, DIM);
    mm_bf16<2, 0><<<dim3(8, 8, NE), 256, 0, stream>>>(h1, w2, bb2, ybuf,
                                                      nullptr, offcnt, SEQ, DIM, FF);
    final_ln_kernel<1><<<dim3(SEQ), 256, 0, stream>>>(h, ybuf, assign_row, topw,
                                                      nullptr, nullptr, g2, b2, out);
  }
}

// Round 15
// 312.704 us; speedup vs baseline: 1.1955x; 1.0027x over previous
//
#include <hip/hip_runtime.h>
#include <hip/hip_bf16.h>
#include <math.h>

#define SEQ 1024
#define DIM 1024
#define NH  16
#define NE  8
#define FF  4096
#define NCH 4

typedef float f32x4 __attribute__((ext_vector_type(4)));
typedef float f32x2 __attribute__((ext_vector_type(2)));
typedef short short8 __attribute__((ext_vector_type(8)));
typedef short s16x4 __attribute__((ext_vector_type(4)));

#define WAIT_VM(N) asm volatile("s_waitcnt vmcnt(" #N ")" ::: "memory")

__device__ __forceinline__ ushort f2bf(float f) {
  union { float f; unsigned u; } v; v.f = f;
  unsigned r = v.u + 0x7FFF + ((v.u >> 16) & 1);
  return (ushort)(r >> 16);
}
__device__ __forceinline__ float bf2f(ushort h) {
  union { unsigned u; float f; } v; v.u = ((unsigned)h) << 16;
  return v.f;
}

__device__ __forceinline__ float gelu_tanh(float x) {
  return 0.5f * x * (1.f + tanhf(0.7978845608028654f * (x + 0.044715f * x * x * x)));
}
__device__ __forceinline__ float gelu_fast(float x) {
  float u = 1.5957691216057308f * (x + 0.044715f * x * x * x);
  return x / (1.f + __expf(-u));
}

__device__ __forceinline__ void gl2lds16(const void* g, void* l) {
  __builtin_amdgcn_global_load_lds(
      (const __attribute__((address_space(1))) unsigned int*)g,
      (__attribute__((address_space(3))) unsigned int*)l, 16, 0, 0);
}

// ---------------------------------------------------------------------------
// Small weight convert+transpose (qkv & o-proj only, hi+lo).
// ---------------------------------------------------------------------------
__global__ __launch_bounds__(256) void wconv_kernel(
    const float* __restrict__ wq, const float* __restrict__ wo,
    ushort* __restrict__ wqT, ushort* __restrict__ wqTl,
    ushort* __restrict__ woT, ushort* __restrict__ woTl) {
  __shared__ __align__(16) ushort th[64 * 64];
  __shared__ __align__(16) ushort tl[64 * 64];
  int z = blockIdx.z, t = threadIdx.x;
  const float* src; ushort* dh; ushort* dl; int R, C, r0, c0;
  if (z == 0) {
    src = wq; dh = wqT; dl = wqTl;
    R = DIM; C = 3 * DIM; r0 = blockIdx.y * 64; c0 = blockIdx.x * 64;
  } else {
    if (blockIdx.x >= 16) return;
    src = wo; dh = woT; dl = woTl;
    R = DIM; C = DIM; r0 = blockIdx.y * 64; c0 = blockIdx.x * 64;
  }
  int ry = (t >> 4) * 4;
  int cx = (t & 15) * 4;
  f32x4 v[4];
#pragma unroll
  for (int j = 0; j < 4; j++)
    v[j] = *(const f32x4*)&src[(size_t)(r0 + ry + j) * C + c0 + cx];
#pragma unroll
  for (int i = 0; i < 4; i++) {
    int trow = cx + i;
    int o = trow * 64 + (((ry >> 3) ^ (trow & 7)) << 3) + (ry & 7);
    ushort uh[4], ul[4];
#pragma unroll
    for (int j = 0; j < 4; j++) {
      float f = v[j][i];
      ushort hh = f2bf(f);
      uh[j] = hh;
      ul[j] = f2bf(f - bf2f(hh));
    }
    *(s16x4*)&th[o] = *(const s16x4*)uh;
    *(s16x4*)&tl[o] = *(const s16x4*)ul;
  }
  __syncthreads();
  int tr = t >> 2, tc = (t & 3) * 16;
  int b0 = (tc >> 3) ^ (tr & 7);
  int b1 = ((tc >> 3) + 1) ^ (tr & 7);
  size_t dbase = (size_t)(c0 + tr) * R + r0 + tc;
  short8 u0 = *(const short8*)&th[tr * 64 + b0 * 8];
  short8 u1 = *(const short8*)&th[tr * 64 + b1 * 8];
  *(short8*)&dh[dbase] = u0;
  *(short8*)&dh[dbase + 8] = u1;
  short8 l0 = *(const short8*)&tl[tr * 64 + b0 * 8];
  short8 l1 = *(const short8*)&tl[tr * 64 + b1 * 8];
  *(short8*)&dl[dbase] = l0;
  *(short8*)&dl[dbase + 8] = l1;
}

// ---------------- fp32 -> bf16 hi/lo split (vectorized) ----------------
__global__ __launch_bounds__(256) void bfsplit_kernel(const float* __restrict__ in,
                                                      ushort* __restrict__ oh,
                                                      ushort* __restrict__ ol) {
  int i = (blockIdx.x * 256 + threadIdx.x) * 4;
  f32x4 v = *(const f32x4*)&in[i];
  ushort h[4], l[4];
#pragma unroll
  for (int j = 0; j < 4; j++) { h[j] = f2bf(v[j]); l[j] = f2bf(v[j] - bf2f(h[j])); }
  *(s16x4*)&oh[i] = *(const s16x4*)h;
  *(s16x4*)&ol[i] = *(const s16x4*)l;
}

// ---------------------------------------------------------------------------
// Fused expert GEMM (r11 structure, 128x128, depth-2 register prefetch).
// ---------------------------------------------------------------------------
#define MM_FEXP_LOAD(ra0v, ra1v, rb0v, rb1v, rb2v, rb3v, T)            \
  { int _ko = (T) * 32;                                                \
    ra0v = *(const short8*)(aG[0] + _ko);                              \
    ra1v = *(const short8*)(aG[1] + _ko);                              \
    rb0v = *(const f32x4*)(bG + (size_t)(_ko + 0) * N);                \
    rb1v = *(const f32x4*)(bG + (size_t)(_ko + 1) * N);                \
    rb2v = *(const f32x4*)(bG + (size_t)(_ko + 2) * N);                \
    rb3v = *(const f32x4*)(bG + (size_t)(_ko + 3) * N); }

#define MM_FEXP_STAGE(buf, ra0v, ra1v, rb0v, rb1v, rb2v, rb3v)         \
  { *(short8*)&As[buf][aw[0]] = ra0v;                                  \
    *(short8*)&As[buf][aw[1]] = ra1v;                                  \
    _Pragma("unroll")                                                  \
    for (int i = 0; i < 4; i++) {                                      \
      ushort u[4];                                                     \
      u[0] = f2bf(rb0v[i]); u[1] = f2bf(rb1v[i]);                      \
      u[2] = f2bf(rb2v[i]); u[3] = f2bf(rb3v[i]);                      \
      *(s16x4*)&Bs[buf][(nb * 4 + i) * 40 + bslot * 4] = *(const s16x4*)u; } }

#define MM_FEXP_MFMA(buf)                                              \
  { short8 af[4], bf[4];                                               \
    _Pragma("unroll")                                                  \
    for (int mi = 0; mi < 4; mi++) af[mi] = *(const short8*)&As[buf][aro[mi]]; \
    _Pragma("unroll")                                                  \
    for (int ni = 0; ni < 4; ni++) bf[ni] = *(const short8*)&Bs[buf][bro[ni]]; \
    _Pragma("unroll")                                                  \
    for (int mi = 0; mi < 4; mi++)                                     \
      _Pragma("unroll")                                                \
      for (int ni = 0; ni < 4; ni++)                                   \
        acc[mi][ni] = __builtin_amdgcn_mfma_f32_16x16x32_bf16(af[mi], bf[ni], acc[mi][ni], 0, 0, 0); }

template <int EPI, int KSPLIT>
__global__ __launch_bounds__(256) void mm_fexp(
    const ushort* __restrict__ A, const float* __restrict__ Bf,
    const float* __restrict__ bias, void* __restrict__ Cout,
    const int* __restrict__ tok, const int* __restrict__ offcnt,
    int N, int K)
{
  int zz = blockIdx.z;
  int e  = (KSPLIT > 1) ? (zz & (NE - 1)) : zz;
  int ks = (KSPLIT > 1) ? (zz >> 3) : 0;
  int off = offcnt[e], cnt = offcnt[NE + e];
  int m0 = blockIdx.y * 128;
  if (m0 >= cnt) return;
  int n0 = blockIdx.x * 128;
  const float* Bp = Bf + (size_t)e * K * N;
  const int Kc = K / KSPLIT, kbase = ks * Kc;

  __shared__ __align__(16) ushort As[2][128 * 32];
  __shared__ __align__(16) ushort Bs[2][128 * 40];

  int t = threadIdx.x, lane = t & 63, w = t >> 6, wr = w >> 1, wc = w & 1;

  const ushort* aG[2]; int aw[2];
#pragma unroll
  for (int c = 0; c < 2; c++) {
    int gid = w * 128 + c * 64 + lane;
    int m = gid >> 2, p = gid & 3;
    int kg = p ^ ((m >> 1) & 3);
    int mc = m0 + m; if (mc > cnt - 1) mc = cnt - 1;
    int arow = tok ? tok[off + mc] : (off + mc);
    aG[c] = A + (size_t)arow * K + kbase + kg * 8;
    aw[c] = gid * 8;
  }

  int kb = t >> 5, nb = t & 31;
  const float* bG = Bp + (size_t)(kbase + kb * 4) * N + n0 + nb * 4;
  int bslot = kb ^ ((nb & 3) << 1);

  int aro[4], bro[4];
#pragma unroll
  for (int mi = 0; mi < 4; mi++) {
    int m = wr * 64 + mi * 16 + (lane & 15);
    aro[mi] = (m * 4 + ((lane >> 4) ^ ((m >> 1) & 3))) * 8;
  }
#pragma unroll
  for (int ni = 0; ni < 4; ni++) {
    int n = wc * 64 + ni * 16 + (lane & 15);
    bro[ni] = n * 40 + ((((lane >> 4) * 2) ^ (((n >> 2) & 3) << 1))) * 4;
  }

  f32x4 acc[4][4] = {};
  const int nt = Kc / 32;

  short8 raA0, raA1, raB0, raB1;
  f32x4 rbA0, rbA1, rbA2, rbA3, rbB0, rbB1, rbB2, rbB3;
  MM_FEXP_LOAD(raA0, raA1, rbA0, rbA1, rbA2, rbA3, 0);
  MM_FEXP_LOAD(raB0, raB1, rbB0, rbB1, rbB2, rbB3, 1);

  for (int tt = 0; tt < nt; tt += 2) {
    MM_FEXP_STAGE(0, raA0, raA1, rbA0, rbA1, rbA2, rbA3);
    if (tt + 2 < nt) MM_FEXP_LOAD(raA0, raA1, rbA0, rbA1, rbA2, rbA3, tt + 2);
    asm volatile("s_waitcnt lgkmcnt(0)" ::: "memory");
    __builtin_amdgcn_sched_barrier(0);
    __builtin_amdgcn_s_barrier();
    MM_FEXP_MFMA(0);
    MM_FEXP_STAGE(1, raB0, raB1, rbB0, rbB1, rbB2, rbB3);
    if (tt + 3 < nt) MM_FEXP_LOAD(raB0, raB1, rbB0, rbB1, rbB2, rbB3, tt + 3);
    asm volatile("s_waitcnt lgkmcnt(0)" ::: "memory");
    __builtin_amdgcn_sched_barrier(0);
    __builtin_amdgcn_s_barrier();
    MM_FEXP_MFMA(1);
  }

  const float* biasp = (EPI == 3) ? nullptr : bias + (size_t)e * N;
  float* Cp = (float*)Cout + (size_t)ks * 2048 * N;
#pragma unroll
  for (int mi = 0; mi < 4; mi++) {
#pragma unroll
    for (int j = 0; j < 4; j++) {
      int grow = m0 + wr * 64 + mi * 16 + (lane >> 4) * 4 + j;
      if (grow >= cnt) continue;
      size_t rbase = (size_t)(off + grow) * N;
#pragma unroll
      for (int ni = 0; ni < 4; ni++) {
        int gcol = n0 + wc * 64 + ni * 16 + (lane & 15);
        float v = acc[mi][ni][j];
        if (EPI == 1) ((ushort*)Cout)[rbase + gcol] = f2bf(gelu_fast(v + biasp[gcol]));
        else          Cp[rbase + gcol] = v;
      }
    }
  }
}

#undef MM_FEXP_LOAD
#undef MM_FEXP_STAGE
#undef MM_FEXP_MFMA

// ---------------------------------------------------------------------------
// Split-precision GEMM (pre-router path).
// ---------------------------------------------------------------------------
__global__ __launch_bounds__(256) void mm_split(
    const ushort* __restrict__ Ah, const ushort* __restrict__ Al,
    const ushort* __restrict__ Bh, const ushort* __restrict__ Bl,
    float* __restrict__ C, int N, int K)
{
  int m0 = blockIdx.y * 128;
  int n0 = blockIdx.x * 128;

  __shared__ __align__(16) ushort Ahs[2][4096], Als[2][4096];
  __shared__ __align__(16) ushort Bhs[2][4096], Bls[2][4096];

  int t = threadIdx.x, lane = t & 63, w = t >> 6, wr = w >> 1, wc = w & 1;

  const ushort *aGh[2], *aGl[2], *bGh[2], *bGl[2];
  int lofs[2];
#pragma unroll
  for (int c = 0; c < 2; c++) {
    int gid = w * 128 + c * 64 + lane;
    int m = gid >> 2, p = gid & 3;
    int kg = p ^ ((m >> 1) & 3);
    aGh[c] = Ah + (size_t)(m0 + m) * K + kg * 8;
    aGl[c] = Al + (size_t)(m0 + m) * K + kg * 8;
    bGh[c] = Bh + (size_t)(n0 + m) * K + kg * 8;
    bGl[c] = Bl + (size_t)(n0 + m) * K + kg * 8;
    lofs[c] = (w * 128 + c * 64) * 8;
  }

  int aro[4], bro[4];
#pragma unroll
  for (int mi = 0; mi < 4; mi++) {
    int m = wr * 64 + mi * 16 + (lane & 15);
    aro[mi] = (m * 4 + ((lane >> 4) ^ ((m >> 1) & 3))) * 8;
  }
#pragma unroll
  for (int ni = 0; ni < 4; ni++) {
    int n = wc * 64 + ni * 16 + (lane & 15);
    bro[ni] = (n * 4 + ((lane >> 4) ^ ((n >> 1) & 3))) * 8;
  }

  f32x4 acc[4][4] = {};
  const int nt = K / 32;

#pragma unroll
  for (int c = 0; c < 2; c++) {
    gl2lds16(aGh[c], &Ahs[0][lofs[c]]); gl2lds16(aGl[c], &Als[0][lofs[c]]);
    gl2lds16(bGh[c], &Bhs[0][lofs[c]]); gl2lds16(bGl[c], &Bls[0][lofs[c]]);
  }
  if (nt > 1) {
#pragma unroll
    for (int c = 0; c < 2; c++) {
      gl2lds16(aGh[c] + 32, &Ahs[1][lofs[c]]); gl2lds16(aGl[c] + 32, &Als[1][lofs[c]]);
      gl2lds16(bGh[c] + 32, &Bhs[1][lofs[c]]); gl2lds16(bGl[c] + 32, &Bls[1][lofs[c]]);
    }
  }

  for (int tt = 0; tt < nt; tt++) {
    if (tt + 1 < nt) WAIT_VM(8); else WAIT_VM(0);
    __builtin_amdgcn_s_barrier();
    int b = tt & 1;
    short8 ah[4], al_[4], bh[4], bl_[4];
#pragma unroll
    for (int mi = 0; mi < 4; mi++) {
      ah[mi] = *(const short8*)&Ahs[b][aro[mi]];
      al_[mi] = *(const short8*)&Als[b][aro[mi]];
    }
#pragma unroll
    for (int ni = 0; ni < 4; ni++) {
      bh[ni] = *(const short8*)&Bhs[b][bro[ni]];
      bl_[ni] = *(const short8*)&Bls[b][bro[ni]];
    }
#pragma unroll
    for (int mi = 0; mi < 4; mi++)
#pragma unroll
      for (int ni = 0; ni < 4; ni++) {
        acc[mi][ni] = __builtin_amdgcn_mfma_f32_16x16x32_bf16(al_[mi], bh[ni], acc[mi][ni], 0, 0, 0);
        acc[mi][ni] = __builtin_amdgcn_mfma_f32_16x16x32_bf16(ah[mi], bl_[ni], acc[mi][ni], 0, 0, 0);
        acc[mi][ni] = __builtin_amdgcn_mfma_f32_16x16x32_bf16(ah[mi], bh[ni], acc[mi][ni], 0, 0, 0);
      }
    asm volatile("s_waitcnt lgkmcnt(0)" ::: "memory");
    __builtin_amdgcn_sched_barrier(0);
    __builtin_amdgcn_s_barrier();
    if (tt + 2 < nt) {
      int ko = (tt + 2) * 32;
#pragma unroll
      for (int c = 0; c < 2; c++) {
        gl2lds16(aGh[c] + ko, &Ahs[b][lofs[c]]); gl2lds16(aGl[c] + ko, &Als[b][lofs[c]]);
        gl2lds16(bGh[c] + ko, &Bhs[b][lofs[c]]); gl2lds16(bGl[c] + ko, &Bls[b][lofs[c]]);
      }
    }
  }

#pragma unroll
  for (int mi = 0; mi < 4; mi++)
#pragma unroll
    for (int j = 0; j < 4; j++) {
      int grow = m0 + wr * 64 + mi * 16 + (lane >> 4) * 4 + j;
      size_t rbase = (size_t)grow * N;
#pragma unroll
      for (int ni = 0; ni < 4; ni++) {
        int gcol = n0 + wc * 64 + ni * 16 + (lane & 15);
        C[rbase + gcol] = acc[mi][ni][j];
      }
    }
}

// ---------------------------------------------------------------------------
// bf16-MFMA GEMM with in-loop conversion (fallback path only).
// ---------------------------------------------------------------------------
template <int EPI, int SPLIT>
__global__ __launch_bounds__(256) void mm_bf16(
    const float* __restrict__ A, const float* __restrict__ B,
    const float* __restrict__ bias, float* __restrict__ C,
    const int* __restrict__ tok, const int* __restrict__ offcnt,
    int M, int N, int K)
{
  int e = blockIdx.z;
  int off = 0, cnt = M;
  if (offcnt) { off = offcnt[e]; cnt = offcnt[NE + e]; }
  int m0 = blockIdx.y * 128;
  if (m0 >= cnt) return;
  const float* Bp = B + (size_t)e * K * N;
  const float* biasp = (EPI == 0) ? nullptr : bias + (size_t)e * N;
  int n0 = blockIdx.x * 128;

  __shared__ __align__(16) ushort As[(SPLIT + 1) * 128 * 32];
  __shared__ __align__(16) ushort Bs[(SPLIT + 1) * 128 * 32];

  int t = threadIdx.x;
  int lane = t & 63;
  int w = t >> 6, wr = w >> 1, wc = w & 1;

  const float* aptr[2];
  int aws[2];
  for (int i = 0; i < 2; i++) {
    int mr = i * 64 + (t >> 2);
    int mc = m0 + mr; if (mc > cnt - 1) mc = cnt - 1;
    int arow = tok ? tok[off + mc] : (off + mc);
    aptr[i] = A + (size_t)arow * K + (t & 3) * 8;
    aws[i] = mr * 32 + (t & 3) * 8;
  }

  int bn = t >> 1, bkh = (t & 1) * 16;
  const float* bptr = Bp + (size_t)bkh * N + n0 + bn;
  int bws0 = bn * 32 + 8 * (((bkh >> 3) + 0) ^ (bn & 3));
  int bws1 = bn * 32 + 8 * (((bkh >> 3) + 1) ^ (bn & 3));

  int aro[4], bro[4];
#pragma unroll
  for (int mi = 0; mi < 4; mi++)
    aro[mi] = (wr * 64 + mi * 16 + (lane & 15)) * 32 + (lane >> 4) * 8;
#pragma unroll
  for (int ni = 0; ni < 4; ni++) {
    int n = wc * 64 + ni * 16 + (lane & 15);
    bro[ni] = n * 32 + 8 * ((lane >> 4) ^ (n & 3));
  }

  f32x4 acc[4][4] = {};

  for (int k0 = 0; k0 < K; k0 += 32) {
#pragma unroll
    for (int i = 0; i < 2; i++) {
      f32x4 v0 = *(const f32x4*)(aptr[i] + k0);
      f32x4 v1 = *(const f32x4*)(aptr[i] + k0 + 4);
      ushort uh[8], ul[8];
#pragma unroll
      for (int j = 0; j < 4; j++) {
        float f0 = v0[j], f1 = v1[j];
        ushort h0 = f2bf(f0), h1 = f2bf(f1);
        uh[j] = h0; uh[4 + j] = h1;
        if (SPLIT) { ul[j] = f2bf(f0 - bf2f(h0)); ul[4 + j] = f2bf(f1 - bf2f(h1)); }
      }
      *(short8*)&As[aws[i]] = *(const short8*)uh;
      if (SPLIT) *(short8*)&As[4096 + aws[i]] = *(const short8*)ul;
    }
    {
      const float* bp = bptr + (size_t)k0 * N;
      ushort uh[16], ul[16];
#pragma unroll
      for (int i = 0; i < 16; i++) {
        float f = bp[(size_t)i * N];
        ushort h = f2bf(f);
        uh[i] = h;
        if (SPLIT) ul[i] = f2bf(f - bf2f(h));
      }
      *(short8*)&Bs[bws0] = *(const short8*)&uh[0];
      *(short8*)&Bs[bws1] = *(const short8*)&uh[8];
      if (SPLIT) {
        *(short8*)&Bs[4096 + bws0] = *(const short8*)&ul[0];
        *(short8*)&Bs[4096 + bws1] = *(const short8*)&ul[8];
      }
    }
    __syncthreads();
    short8 afh[4], bfh[4], afl[4], bfl[4];
#pragma unroll
    for (int mi = 0; mi < 4; mi++) {
      afh[mi] = *(const short8*)&As[aro[mi]];
      if (SPLIT) afl[mi] = *(const short8*)&As[4096 + aro[mi]];
    }
#pragma unroll
    for (int ni = 0; ni < 4; ni++) {
      bfh[ni] = *(const short8*)&Bs[bro[ni]];
      if (SPLIT) bfl[ni] = *(const short8*)&Bs[4096 + bro[ni]];
    }
#pragma unroll
    for (int mi = 0; mi < 4; mi++)
#pragma unroll
      for (int ni = 0; ni < 4; ni++) {
        if (SPLIT) {
          acc[mi][ni] = __builtin_amdgcn_mfma_f32_16x16x32_bf16(afl[mi], bfh[ni], acc[mi][ni], 0, 0, 0);
          acc[mi][ni] = __builtin_amdgcn_mfma_f32_16x16x32_bf16(afh[mi], bfl[ni], acc[mi][ni], 0, 0, 0);
        }
        acc[mi][ni] = __builtin_amdgcn_mfma_f32_16x16x32_bf16(afh[mi], bfh[ni], acc[mi][ni], 0, 0, 0);
      }
    __syncthreads();
  }

#pragma unroll
  for (int mi = 0; mi < 4; mi++) {
#pragma unroll
    for (int j = 0; j < 4; j++) {
      int grow = m0 + wr * 64 + mi * 16 + (lane >> 4) * 4 + j;
      if (grow >= cnt) continue;
      size_t rbase = (size_t)(off + grow) * N;
#pragma unroll
      for (int ni = 0; ni < 4; ni++) {
        int gcol = n0 + wc * 64 + ni * 16 + (lane & 15);
        float v = acc[mi][ni][j];
        if (EPI >= 1) v += biasp[gcol];
        if (EPI == 1) v = gelu_tanh(v);
        C[rbase + gcol] = v;
      }
    }
  }
}

// ---------------------------------------------------------------------------
// MFMA flash attention, split-bf16, KV-chunked (NCH chunks per q-block).
// Grid (8 qb, NCH ch, 16 heads). Chunk ch covers tiles [ch*ntot/NCH,
// (ch+1)*ntot/NCH) of ntot = 2*(qb+1). Empty chunks write m=-1e30, l=0, O=0
// -> weight exp(m-M)=0 at combine.
// ---------------------------------------------------------------------------
__device__ __forceinline__ int vidx(int d, int key) {
  return d * 64 + ((((key >> 3) ^ (d & 7)) << 3) | (key & 7));
}

__global__ __launch_bounds__(256, 1) void attn_mfma(const float* __restrict__ qkv,
                                                    float* __restrict__ opart,
                                                    float* __restrict__ ml) {
  const int qb = blockIdx.x;
  const int ch = blockIdx.y;
  const int head = blockIdx.z;
  const int q0 = qb * 128;
  const int t = threadIdx.x;
  const int lane = t & 63, w = t >> 6;
  const int g = lane >> 4, l4 = lane & 15;

  __shared__ __align__(16) ushort Kh[64 * 64], Kl[64 * 64];
  __shared__ __align__(16) ushort Vh[64 * 64], Vl[64 * 64];
  __shared__ __align__(16) ushort Ph[4][32 * 72], Pl[4][32 * 72];

  short8 qh[2][2], ql[2][2];
#pragma unroll
  for (int mi = 0; mi < 2; mi++)
#pragma unroll
    for (int ks = 0; ks < 2; ks++) {
      int row = q0 + w * 32 + mi * 16 + l4;
      const float* qp = qkv + (size_t)row * 3072 + head * 64 + ks * 32 + g * 8;
      f32x4 a = *(const f32x4*)qp;
      f32x4 b4 = *(const f32x4*)(qp + 4);
      ushort uh[8], ul_[8];
#pragma unroll
      for (int j = 0; j < 4; j++) {
        ushort h0 = f2bf(a[j]), h1 = f2bf(b4[j]);
        uh[j] = h0; uh[4 + j] = h1;
        ul_[j] = f2bf(a[j] - bf2f(h0)); ul_[4 + j] = f2bf(b4[j] - bf2f(h1));
      }
      qh[mi][ks] = *(const short8*)uh;
      ql[mi][ks] = *(const short8*)ul_;
    }

  float m_s[2][4], l_s[2][4];
  f32x4 O[2][4] = {};
#pragma unroll
  for (int mi = 0; mi < 2; mi++)
#pragma unroll
    for (int j = 0; j < 4; j++) { m_s[mi][j] = -1e30f; l_s[mi][j] = 0.f; }

  const int ntot = 2 * (qb + 1);
  const int kt_beg = (ch * ntot) / NCH;
  const int kt_end = ((ch + 1) * ntot) / NCH;
  for (int kt = kt_beg; kt < kt_end; kt++) {
    const int kv0 = kt * 64;
    __syncthreads();
    {
      int key = t >> 2;
      int dblk = (t & 3) * 16;
      const float* kp = qkv + (size_t)(kv0 + key) * 3072 + 1024 + head * 64 + dblk;
      const float* vp = kp + 1024;
      f32x4 k0 = *(const f32x4*)kp, k1 = *(const f32x4*)(kp + 4),
            k2 = *(const f32x4*)(kp + 8), k3 = *(const f32x4*)(kp + 12);
      f32x4 v0 = *(const f32x4*)vp, v1 = *(const f32x4*)(vp + 4),
            v2 = *(const f32x4*)(vp + 8), v3 = *(const f32x4*)(vp + 12);
      float kf[16] = {k0[0],k0[1],k0[2],k0[3], k1[0],k1[1],k1[2],k1[3],
                      k2[0],k2[1],k2[2],k2[3], k3[0],k3[1],k3[2],k3[3]};
      float vf[16] = {v0[0],v0[1],v0[2],v0[3], v1[0],v1[1],v1[2],v1[3],
                      v2[0],v2[1],v2[2],v2[3], v3[0],v3[1],v3[2],v3[3]};
#pragma unroll
      for (int half = 0; half < 2; half++) {
        int d8 = (dblk >> 3) + half;
        int idx = key * 64 + ((d8 ^ (key & 7)) << 3);
        ushort uh[8], ul_[8];
#pragma unroll
        for (int j = 0; j < 8; j++) {
          float f = kf[half * 8 + j];
          ushort h = f2bf(f);
          uh[j] = h; ul_[j] = f2bf(f - bf2f(h));
        }
        *(short8*)&Kh[idx] = *(const short8*)uh;
        *(short8*)&Kl[idx] = *(const short8*)ul_;
      }
#pragma unroll
      for (int i = 0; i < 16; i++) {
        int d = dblk + i;
        int idx = vidx(d, key);
        float f = vf[i];
        ushort h = f2bf(f);
        Vh[idx] = h; Vl[idx] = f2bf(f - bf2f(h));
      }
    }
    __syncthreads();

    if (kv0 <= q0 + w * 32 + 31) {
      f32x4 S[2][4] = {};
#pragma unroll
      for (int ks = 0; ks < 2; ks++) {
        short8 kbh[4], kbl[4];
#pragma unroll
        for (int ni = 0; ni < 4; ni++) {
          int key = ni * 16 + l4;
          int d8 = ks * 4 + g;
          int idx = key * 64 + ((d8 ^ (key & 7)) << 3);
          kbh[ni] = *(const short8*)&Kh[idx];
          kbl[ni] = *(const short8*)&Kl[idx];
        }
#pragma unroll
        for (int mi = 0; mi < 2; mi++)
#pragma unroll
          for (int ni = 0; ni < 4; ni++) {
            S[mi][ni] = __builtin_amdgcn_mfma_f32_16x16x32_bf16(ql[mi][ks], kbh[ni], S[mi][ni], 0, 0, 0);
            S[mi][ni] = __builtin_amdgcn_mfma_f32_16x16x32_bf16(qh[mi][ks], kbl[ni], S[mi][ni], 0, 0, 0);
            S[mi][ni] = __builtin_amdgcn_mfma_f32_16x16x32_bf16(qh[mi][ks], kbh[ni], S[mi][ni], 0, 0, 0);
          }
      }
#pragma unroll
      for (int mi = 0; mi < 2; mi++) {
        int rowb = q0 + w * 32 + mi * 16 + g * 4;
        float mx[4] = {-1e30f, -1e30f, -1e30f, -1e30f};
#pragma unroll
        for (int ni = 0; ni < 4; ni++) {
          int col = kv0 + ni * 16 + l4;
#pragma unroll
          for (int j = 0; j < 4; j++) {
            float s = S[mi][ni][j] * 0.125f;
            if (col > rowb + j) s = -1e30f;
            S[mi][ni][j] = s;
            mx[j] = fmaxf(mx[j], s);
          }
        }
#pragma unroll
        for (int j = 0; j < 4; j++) {
#pragma unroll
          for (int msk = 8; msk; msk >>= 1) mx[j] = fmaxf(mx[j], __shfl_xor(mx[j], msk));
          float mn = fmaxf(m_s[mi][j], mx[j]);
          float sc = __expf(m_s[mi][j] - mn);
          m_s[mi][j] = mn;
          l_s[mi][j] *= sc;
#pragma unroll
          for (int df = 0; df < 4; df++) O[mi][df][j] *= sc;
        }
        float ps[4] = {0.f, 0.f, 0.f, 0.f};
#pragma unroll
        for (int ni = 0; ni < 4; ni++)
#pragma unroll
          for (int j = 0; j < 4; j++) {
            float p = __expf(S[mi][ni][j] - m_s[mi][j]);
            ps[j] += p;
            int rl = mi * 16 + g * 4 + j, cl = ni * 16 + l4;
            ushort h = f2bf(p);
            Ph[w][rl * 72 + cl] = h;
            Pl[w][rl * 72 + cl] = f2bf(p - bf2f(h));
          }
#pragma unroll
        for (int j = 0; j < 4; j++) {
#pragma unroll
          for (int msk = 8; msk; msk >>= 1) ps[j] += __shfl_xor(ps[j], msk);
          l_s[mi][j] += ps[j];
        }
      }
      asm volatile("s_waitcnt lgkmcnt(0)" ::: "memory");
      __builtin_amdgcn_sched_barrier(0);
#pragma unroll
      for (int ks = 0; ks < 2; ks++) {
        short8 pah[2], pal[2], vbh[4], vbl[4];
#pragma unroll
        for (int mi = 0; mi < 2; mi++) {
          int idx = (mi * 16 + l4) * 72 + ks * 32 + g * 8;
          pah[mi] = *(const short8*)&Ph[w][idx];
          pal[mi] = *(const short8*)&Pl[w][idx];
        }
#pragma unroll
        for (int df = 0; df < 4; df++) {
          int d = df * 16 + l4;
          int k8 = ks * 4 + g;
          int idx = d * 64 + ((k8 ^ (d & 7)) << 3);
          vbh[df] = *(const short8*)&Vh[idx];
          vbl[df] = *(const short8*)&Vl[idx];
        }
#pragma unroll
        for (int mi = 0; mi < 2; mi++)
#pragma unroll
          for (int df = 0; df < 4; df++) {
            O[mi][df] = __builtin_amdgcn_mfma_f32_16x16x32_bf16(pal[mi], vbh[df], O[mi][df], 0, 0, 0);
            O[mi][df] = __builtin_amdgcn_mfma_f32_16x16x32_bf16(pah[mi], vbl[df], O[mi][df], 0, 0, 0);
            O[mi][df] = __builtin_amdgcn_mfma_f32_16x16x32_bf16(pah[mi], vbh[df], O[mi][df], 0, 0, 0);
          }
      }
    }
  }

  // ---- write partials ----
#pragma unroll
  for (int mi = 0; mi < 2; mi++)
#pragma unroll
    for (int j = 0; j < 4; j++) {
      int row = q0 + w * 32 + mi * 16 + g * 4 + j;
      if (l4 == 0) {
        float* mlp = ml + (((size_t)ch * NH + head) * SEQ + row) * 2;
        mlp[0] = m_s[mi][j];
        mlp[1] = l_s[mi][j];
      }
#pragma unroll
      for (int df = 0; df < 4; df++)
        opart[(size_t)ch * (SEQ * DIM) + (size_t)row * DIM + head * 64 + df * 16 + l4] =
            O[mi][df][j];
    }
}

// ---- combine NCH KV-chunk partials -> bf16 hi/lo (fast) or fp32 (fallback) --
template <int SPLIT>
__global__ __launch_bounds__(256) void attn_combine(const float* __restrict__ opart,
                                                    const float* __restrict__ ml,
                                                    float* __restrict__ o,
                                                    ushort* __restrict__ oh,
                                                    ushort* __restrict__ ol) {
  int row = blockIdx.x, t = threadIdx.x;
  int d0 = t * 4;
  int head = d0 >> 6;
  float m[NCH], l[NCH];
#pragma unroll
  for (int ch = 0; ch < NCH; ch++) {
    const float* p = ml + (((size_t)ch * NH + head) * SEQ + row) * 2;
    m[ch] = p[0]; l[ch] = p[1];
  }
  float M = m[0];
#pragma unroll
  for (int ch = 1; ch < NCH; ch++) M = fmaxf(M, m[ch]);
  float wgt[NCH], den = 0.f;
#pragma unroll
  for (int ch = 0; ch < NCH; ch++) { wgt[ch] = __expf(m[ch] - M); den += l[ch] * wgt[ch]; }
  float inv = 1.f / den;
  f32x4 r = {0.f, 0.f, 0.f, 0.f};
#pragma unroll
  for (int ch = 0; ch < NCH; ch++) {
    f32x4 O = *(const f32x4*)&opart[(size_t)ch * (SEQ * DIM) + (size_t)row * DIM + d0];
#pragma unroll
    for (int j = 0; j < 4; j++) r[j] += O[j] * wgt[ch];
  }
#pragma unroll
  for (int j = 0; j < 4; j++) r[j] *= inv;
  if (SPLIT) {
    ushort hh[4], ll[4];
#pragma unroll
    for (int j = 0; j < 4; j++) { hh[j] = f2bf(r[j]); ll[j] = f2bf(r[j] - bf2f(hh[j])); }
    *(s16x4*)&oh[(size_t)row * DIM + d0] = *(const s16x4*)hh;
    *(s16x4*)&ol[(size_t)row * DIM + d0] = *(const s16x4*)ll;
  } else {
    *(f32x4*)&o[(size_t)row * DIM + d0] = r;
  }
}

// ---------------- block reduce helper ----------------
__device__ float block_reduce_256(float v, float* red, int t) {
  red[t] = v; __syncthreads();
  for (int st = 128; st > 0; st >>= 1) {
    if (t < st) red[t] += red[t + st];
    __syncthreads();
  }
  float r = red[0];
  __syncthreads();
  return r;
}

// ---- h = LN(x + r) * g + b, bf16 copy, + fused router top-2 (fast path) ----
__global__ __launch_bounds__(256) void addln_router_kernel(
    const float* __restrict__ x, const float* __restrict__ r,
    const float* __restrict__ g, const float* __restrict__ b,
    const float* __restrict__ wg,
    float* __restrict__ out, ushort* __restrict__ outb,
    int* __restrict__ topi, float* __restrict__ topw) {
  __shared__ float red[256];
  __shared__ float red2[NE][256];
  int row = blockIdx.x, t = threadIdx.x;
  float vals[4];
  float s = 0.f;
  for (int i = 0; i < 4; i++) {
    int d = t + i * 256;
    vals[i] = x[(size_t)row * DIM + d] + r[(size_t)row * DIM + d];
    s += vals[i];
  }
  float mean = block_reduce_256(s, red, t) * (1.f / DIM);
  float vs = 0.f;
  for (int i = 0; i < 4; i++) { float d = vals[i] - mean; vs += d * d; }
  float var = block_reduce_256(vs, red, t) * (1.f / DIM);
  float inv = rsqrtf(var + 1e-5f);
  float hv4[4];
  for (int i = 0; i < 4; i++) {
    int d = t + i * 256;
    float v = (vals[i] - mean) * inv * g[d] + b[d];
    hv4[i] = v;
    out[(size_t)row * DIM + d] = v;
    outb[(size_t)row * DIM + d] = f2bf(v);
  }
  // router (identical arithmetic to the standalone kernel)
  float acc[NE] = {};
  for (int i = 0; i < 4; i++) {
    int d = t + i * 256;
    const float* wr = wg + (size_t)d * NE;
    for (int e = 0; e < NE; e++) acc[e] += hv4[i] * wr[e];
  }
  for (int e = 0; e < NE; e++) red2[e][t] = acc[e];
  __syncthreads();
  for (int st = 128; st > 0; st >>= 1) {
    if (t < st)
      for (int e = 0; e < NE; e++) red2[e][t] += red2[e][t + st];
    __syncthreads();
  }
  if (t == 0) {
    float l[NE];
    for (int e = 0; e < NE; e++) l[e] = red2[e][0];
    int i0 = 0;
    for (int e = 1; e < NE; e++) if (l[e] > l[i0]) i0 = e;
    int i1 = -1;
    for (int e = 0; e < NE; e++) {
      if (e == i0) continue;
      if (i1 < 0 || l[e] > l[i1]) i1 = e;
    }
    float p1 = __expf(l[i1] - l[i0]);
    float iv = 1.f / (1.f + p1);
    topi[row * 2] = i0; topi[row * 2 + 1] = i1;
    topw[row * 2] = iv; topw[row * 2 + 1] = p1 * iv;
  }
}

// ---------------- h = LN(x + r) * g + b  (fallback) ----------------
__global__ __launch_bounds__(256) void addln_kernel(const float* __restrict__ x,
                                                    const float* __restrict__ r,
                                                    const float* __restrict__ g,
                                                    const float* __restrict__ b,
                                                    float* __restrict__ out,
                                                    ushort* __restrict__ outb) {
  __shared__ float red[256];
  int row = blockIdx.x, t = threadIdx.x;
  float vals[4];
  float s = 0.f;
  for (int i = 0; i < 4; i++) {
    int d = t + i * 256;
    vals[i] = x[(size_t)row * DIM + d] + r[(size_t)row * DIM + d];
    s += vals[i];
  }
  float mean = block_reduce_256(s, red, t) * (1.f / DIM);
  float vs = 0.f;
  for (int i = 0; i < 4; i++) { float d = vals[i] - mean; vs += d * d; }
  float var = block_reduce_256(vs, red, t) * (1.f / DIM);
  float inv = rsqrtf(var + 1e-5f);
  for (int i = 0; i < 4; i++) {
    int d = t + i * 256;
    float v = (vals[i] - mean) * inv * g[d] + b[d];
    out[(size_t)row * DIM + d] = v;
    if (outb) outb[(size_t)row * DIM + d] = f2bf(v);
  }
}

// ---------------- router (fallback) ----------------
__global__ __launch_bounds__(256) void router_kernel(const float* __restrict__ h,
                                                     const float* __restrict__ wg,
                                                     int* __restrict__ topi,
                                                     float* __restrict__ topw) {
  __shared__ float red[NE][256];
  int tkn = blockIdx.x, t = threadIdx.x;
  float acc[NE] = {};
  for (int i = 0; i < 4; i++) {
    int d = t + i * 256;
    float hv = h[(size_t)tkn * DIM + d];
    const float* wr = wg + (size_t)d * NE;
    for (int e = 0; e < NE; e++) acc[e] += hv * wr[e];
  }
  for (int e = 0; e < NE; e++) red[e][t] = acc[e];
  __syncthreads();
  for (int st = 128; st > 0; st >>= 1) {
    if (t < st)
      for (int e = 0; e < NE; e++) red[e][t] += red[e][t + st];
    __syncthreads();
  }
  if (t == 0) {
    float l[NE];
    for (int e = 0; e < NE; e++) l[e] = red[e][0];
    int i0 = 0;
    for (int e = 1; e < NE; e++) if (l[e] > l[i0]) i0 = e;
    int i1 = -1;
    for (int e = 0; e < NE; e++) {
      if (e == i0) continue;
      if (i1 < 0 || l[e] > l[i1]) i1 = e;
    }
    float p1 = __expf(l[i1] - l[i0]);
    float inv = 1.f / (1.f + p1);
    topi[tkn * 2] = i0; topi[tkn * 2 + 1] = i1;
    topw[tkn * 2] = inv; topw[tkn * 2 + 1] = p1 * inv;
  }
}

// ---------------- deterministic per-expert compaction (1 block) ----------------
__global__ __launch_bounds__(1024) void compact_kernel(const int* __restrict__ topi,
                                                       int* __restrict__ tok,
                                                       int* __restrict__ assign_row,
                                                       int* __restrict__ offcnt) {
  __shared__ int scan[1024];
  __shared__ int sbase;
  int t = threadIdx.x;
  if (t == 0) sbase = 0;
  __syncthreads();
  for (int e = 0; e < NE; e++) {
    int which = -1;
    if (topi[t * 2] == e) which = 0;
    else if (topi[t * 2 + 1] == e) which = 1;
    scan[t] = (which >= 0) ? 1 : 0;
    __syncthreads();
    for (int s2 = 1; s2 < 1024; s2 <<= 1) {
      int add = (t >= s2) ? scan[t - s2] : 0;
      __syncthreads();
      scan[t] += add;
      __syncthreads();
    }
    int incl = scan[t];
    int total = scan[1023];
    int base = sbase;
    if (which >= 0) {
      int pos = base + incl - 1;
      tok[pos] = t;
      assign_row[t * 2 + which] = pos;
    }
    if (t == 0) { offcnt[e] = base; offcnt[NE + e] = total; }
    __syncthreads();
    if (t == 0) sbase = base + total;
    __syncthreads();
  }
}

// ---------------- final: out = LN(h + combine(moe)) ----------------
template <int KS>
__global__ __launch_bounds__(256) void final_ln_kernel(const float* __restrict__ h,
                                                       const float* __restrict__ y,
                                                       const int* __restrict__ assign_row,
                                                       const float* __restrict__ topw,
                                                       const int* __restrict__ topi,
                                                       const float* __restrict__ bb2,
                                                       const float* __restrict__ g,
                                                       const float* __restrict__ b,
                                                       float* __restrict__ out) {
  __shared__ float red[256];
  int row = blockIdx.x, t = threadIdx.x;
  int r0 = assign_row[row * 2], r1 = assign_row[row * 2 + 1];
  float w0 = topw[row * 2], w1 = topw[row * 2 + 1];
  float vals[4];
  float s = 0.f;
  for (int i = 0; i < 4; i++) {
    int d = t + i * 256;
    float acc0 = 0.f, acc1 = 0.f;
#pragma unroll
    for (int p = 0; p < KS; p++) {
      acc0 += y[(size_t)p * 2048 * DIM + (size_t)r0 * DIM + d];
      acc1 += y[(size_t)p * 2048 * DIM + (size_t)r1 * DIM + d];
    }
    float v = h[(size_t)row * DIM + d] + w0 * acc0 + w1 * acc1;
    if (KS > 1) {
      int e0 = topi[row * 2], e1 = topi[row * 2 + 1];
      v += w0 * bb2[e0 * DIM + d] + w1 * bb2[e1 * DIM + d];
    }
    vals[i] = v;
    s += v;
  }
  float mean = block_reduce_256(s, red, t) * (1.f / DIM);
  float vs = 0.f;
  for (int i = 0; i < 4; i++) { float d = vals[i] - mean; vs += d * d; }
  float var = block_reduce_256(vs, red, t) * (1.f / DIM);
  float inv = rsqrtf(var + 1e-5f);
  for (int i = 0; i < 4; i++) {
    int d = t + i * 256;
    out[(size_t)row * DIM + d] = (vals[i] - mean) * inv * g[d] + b[d];
  }
}

extern "C" void kernel_launch(void* const* d_in, const int* in_sizes, int n_in,
                              void* d_out, int out_size, void* d_ws, size_t ws_size,
                              hipStream_t stream) {
  const float* x     = (const float*)d_in[0];
  const float* w_qkv = (const float*)d_in[1];
  const float* w_o   = (const float*)d_in[2];
  const float* g1    = (const float*)d_in[3];
  const float* b1    = (const float*)d_in[4];
  const float* wg    = (const float*)d_in[5];
  const float* w1    = (const float*)d_in[6];
  const float* bb1   = (const float*)d_in[7];
  const float* w2    = (const float*)d_in[8];
  const float* bb2   = (const float*)d_in[9];
  const float* g2    = (const float*)d_in[10];
  const float* b2    = (const float*)d_in[11];
  float* out = (float*)d_out;
  float* ws = (float*)d_ws;

  const bool fast = ws_size >= (size_t)46671872 * 4;

  if (fast) {
    float* qkv    = ws;                       // 3,145,728 f
    float* oproj  = ws + 4194304;             // 1,048,576 f
    float* h      = ws + 5242880;             // 1,048,576 f
    float* ybuf   = ws + 6291456;             // 2,097,152 f (xh/xl/oh/ol aliases)
    float* topw   = ws + 8388608;             // 2,048 f
    int*   ibase  = (int*)(ws + 8390656);     // 8,192 ints
    int* topi       = ibase;
    int* tok        = ibase + 2048;
    int* assign_row = ibase + 4096;
    int* offcnt     = ibase + 6144;
    ushort* hb  = (ushort*)(ws + 8398848);    // 1,048,576 us
    ushort* h1b = (ushort*)(ws + 8923136);    // 8,388,608 us
    ushort* wqT  = (ushort*)(ws + 13117440);  // 3,145,728 us
    ushort* wqTl = wqT + 3145728;             // 3,145,728 us
    ushort* woT  = wqT + 6291456;             // 1,048,576 us
    ushort* woTl = wqT + 7340032;             // 1,048,576 us  (ends at f 17,311,744)
    float* ypart = ws + 17311744;             // 8,388,608 f (32 MB K-split partials)
    ushort* xh = (ushort*)ybuf;               // activation split aliases
    ushort* xl = xh + 1048576;
    ushort* oh = xh + 2097152;
    ushort* ol = xh + 3145728;
    // attn partials alias the ypart region (dead until step 8)
    float* opart = ypart;                     // NCH x 1,048,576 f
    float* mlbuf = ypart + NCH * 1048576;     // 131,072 f

    // 0. small weight convert/transpose (qkv & o-proj, hi+lo)
    wconv_kernel<<<dim3(48, 16, 2), 256, 0, stream>>>(w_qkv, w_o,
                                                      wqT, wqTl, woT, woTl);
    // 0b. split x
    bfsplit_kernel<<<dim3(SEQ * DIM / 1024), 256, 0, stream>>>(x, xh, xl);
    // 1. qkv = x @ w_qkv  (pipelined split GEMM)
    mm_split<<<dim3(24, 8), 256, 0, stream>>>(xh, xl, wqT, wqTl, qkv, 3 * DIM, DIM);
    // 2. attention (4-way KV chunks: 512 balanced blocks) + fused combine/split
    attn_mfma<<<dim3(8, NCH, NH), 256, 0, stream>>>(qkv, opart, mlbuf);
    attn_combine<1><<<dim3(SEQ), 256, 0, stream>>>(opart, mlbuf, nullptr, oh, ol);
    // 3. oproj = attn_o @ w_o
    mm_split<<<dim3(8, 8), 256, 0, stream>>>(oh, ol, woT, woTl, oproj, DIM, DIM);
    // 4. h = LN(x + oproj) + bf16 copy + fused router
    addln_router_kernel<<<dim3(SEQ), 256, 0, stream>>>(x, oproj, g1, b1, wg,
                                                       h, hb, topi, topw);
    // 5. compaction
    compact_kernel<<<dim3(1), 1024, 0, stream>>>(topi, tok, assign_row, offcnt);
    // 6. expert up+gelu -> bf16
    mm_fexp<1, 1><<<dim3(FF / 128, 8, NE), 256, 0, stream>>>(hb, w1, bb1, (void*)h1b,
                                                             tok, offcnt, FF, DIM);
    // 7. expert down, K-split 4 -> fp32 partials (overwrites opart/ml; dead)
    mm_fexp<3, 4><<<dim3(DIM / 128, 8, NE * 4), 256, 0, stream>>>(h1b, w2, nullptr,
                                                                  (void*)ypart,
                                                                  nullptr, offcnt, DIM, FF);
    // 8. combine partials + bb2 + residual + LN
    final_ln_kernel<4><<<dim3(SEQ), 256, 0, stream>>>(h, ypart, assign_row, topw,
                                                      topi, bb2, g2, b2, out);
  } else {
    float* qkv    = ws;
    float* attn_o = ws + 3145728;
    float* oproj  = ws + 4194304;
    float* h      = ws + 5242880;
    float* h1     = ws + 6291456;              // 8,388,608 f
    float* ybuf   = ws + 14680064;
    float* topw   = ws + 16777216;
    int*   ibase  = (int*)(ws + 16779264);
    int* topi       = ibase;
    int* tok        = ibase + 2048;
    int* assign_row = ibase + 4096;
    int* offcnt     = ibase + 6144;
    float* opart = h1;                         // alias (dead until expert GEMMs)
    float* mlbuf = h1 + NCH * 1048576;

    mm_bf16<0, 1><<<dim3(24, 8, 1), 256, 0, stream>>>(x, w_qkv, nullptr, qkv,
                                                      nullptr, nullptr, SEQ, 3 * DIM, DIM);
    attn_mfma<<<dim3(8, NCH, NH), 256, 0, stream>>>(qkv, opart, mlbuf);
    attn_combine<0><<<dim3(SEQ), 256, 0, stream>>>(opart, mlbuf, attn_o, nullptr, nullptr);
    mm_bf16<0, 1><<<dim3(8, 8, 1), 256, 0, stream>>>(attn_o, w_o, nullptr, oproj,
                                                     nullptr, nullptr, SEQ, DIM, DIM);
    addln_kernel<<<dim3(SEQ), 256, 0, stream>>>(x, oproj, g1, b1, h, nullptr);
    router_kernel<<<dim3(SEQ), 256, 0, stream>>>(h, wg, topi, topw);
    compact_kernel<<<dim3(1), 1024, 0, stream>>>(topi, tok, assign_row, offcnt);
    mm_bf16<1, 0><<<dim3(32, 8, NE), 256, 0, stream>>>(h, w1, bb1, h1,
                                                       tok, offcnt, SEQ, FF, DIM);
    mm_bf16<2, 0><<<dim3(8, 8, NE), 256, 0, stream>>>(h1, w2, bb2, ybuf,
                                                      nullptr, offcnt, SEQ, DIM, FF);
    final_ln_kernel<1><<<dim3(SEQ), 256, 0, stream>>>(h, ybuf, assign_row, topw,
                                                      nullptr, nullptr, g2, b2, out);
  }
}

// Round 16
// 311.298 us; speedup vs baseline: 1.2009x; 1.0045x over previous
//
#include <hip/hip_runtime.h>
#include <hip/hip_bf16.h>
#include <math.h>

#define SEQ 1024
#define DIM 1024
#define NH  16
#define NE  8
#define FF  4096
#define NCH 8

typedef float f32x4 __attribute__((ext_vector_type(4)));
typedef float f32x2 __attribute__((ext_vector_type(2)));
typedef short short8 __attribute__((ext_vector_type(8)));
typedef short s16x4 __attribute__((ext_vector_type(4)));

#define WAIT_VM(N) asm volatile("s_waitcnt vmcnt(" #N ")" ::: "memory")

__device__ __forceinline__ ushort f2bf(float f) {
  union { float f; unsigned u; } v; v.f = f;
  unsigned r = v.u + 0x7FFF + ((v.u >> 16) & 1);
  return (ushort)(r >> 16);
}
__device__ __forceinline__ float bf2f(ushort h) {
  union { unsigned u; float f; } v; v.u = ((unsigned)h) << 16;
  return v.f;
}

__device__ __forceinline__ float gelu_tanh(float x) {
  return 0.5f * x * (1.f + tanhf(0.7978845608028654f * (x + 0.044715f * x * x * x)));
}
__device__ __forceinline__ float gelu_fast(float x) {
  float u = 1.5957691216057308f * (x + 0.044715f * x * x * x);
  return x / (1.f + __expf(-u));
}

__device__ __forceinline__ void gl2lds16(const void* g, void* l) {
  __builtin_amdgcn_global_load_lds(
      (const __attribute__((address_space(1))) unsigned int*)g,
      (__attribute__((address_space(3))) unsigned int*)l, 16, 0, 0);
}

// ---------------------------------------------------------------------------
// Weight convert+transpose (qkv & o-proj, hi+lo) + fused x bf-split (z=2).
// grid (64, 16, 3).
// ---------------------------------------------------------------------------
__global__ __launch_bounds__(256) void wconv_kernel(
    const float* __restrict__ wq, const float* __restrict__ wo,
    const float* __restrict__ x,
    ushort* __restrict__ wqT, ushort* __restrict__ wqTl,
    ushort* __restrict__ woT, ushort* __restrict__ woTl,
    ushort* __restrict__ xh, ushort* __restrict__ xl) {
  __shared__ __align__(16) ushort th[64 * 64];
  __shared__ __align__(16) ushort tl[64 * 64];
  int z = blockIdx.z, t = threadIdx.x;
  if (z == 2) {           // bfsplit of x: 1024 virtual blocks
    int blk = blockIdx.y * 64 + blockIdx.x;
    int i = (blk * 256 + t) * 4;
    f32x4 v = *(const f32x4*)&x[i];
    ushort h[4], l[4];
#pragma unroll
    for (int j = 0; j < 4; j++) { h[j] = f2bf(v[j]); l[j] = f2bf(v[j] - bf2f(h[j])); }
    *(s16x4*)&xh[i] = *(const s16x4*)h;
    *(s16x4*)&xl[i] = *(const s16x4*)l;
    return;
  }
  const float* src; ushort* dh; ushort* dl; int R, C, r0, c0;
  if (z == 0) {
    if (blockIdx.x >= 48) return;
    src = wq; dh = wqT; dl = wqTl;
    R = DIM; C = 3 * DIM; r0 = blockIdx.y * 64; c0 = blockIdx.x * 64;
  } else {
    if (blockIdx.x >= 16) return;
    src = wo; dh = woT; dl = woTl;
    R = DIM; C = DIM; r0 = blockIdx.y * 64; c0 = blockIdx.x * 64;
  }
  int ry = (t >> 4) * 4;
  int cx = (t & 15) * 4;
  f32x4 v[4];
#pragma unroll
  for (int j = 0; j < 4; j++)
    v[j] = *(const f32x4*)&src[(size_t)(r0 + ry + j) * C + c0 + cx];
#pragma unroll
  for (int i = 0; i < 4; i++) {
    int trow = cx + i;
    int o = trow * 64 + (((ry >> 3) ^ (trow & 7)) << 3) + (ry & 7);
    ushort uh[4], ul[4];
#pragma unroll
    for (int j = 0; j < 4; j++) {
      float f = v[j][i];
      ushort hh = f2bf(f);
      uh[j] = hh;
      ul[j] = f2bf(f - bf2f(hh));
    }
    *(s16x4*)&th[o] = *(const s16x4*)uh;
    *(s16x4*)&tl[o] = *(const s16x4*)ul;
  }
  __syncthreads();
  int tr = t >> 2, tc = (t & 3) * 16;
  int b0 = (tc >> 3) ^ (tr & 7);
  int b1 = ((tc >> 3) + 1) ^ (tr & 7);
  size_t dbase = (size_t)(c0 + tr) * R + r0 + tc;
  short8 u0 = *(const short8*)&th[tr * 64 + b0 * 8];
  short8 u1 = *(const short8*)&th[tr * 64 + b1 * 8];
  *(short8*)&dh[dbase] = u0;
  *(short8*)&dh[dbase + 8] = u1;
  short8 l0 = *(const short8*)&tl[tr * 64 + b0 * 8];
  short8 l1 = *(const short8*)&tl[tr * 64 + b1 * 8];
  *(short8*)&dl[dbase] = l0;
  *(short8*)&dl[dbase + 8] = l1;
}

// ---------------- fp32 -> bf16 hi/lo split (fallback path) ----------------
__global__ __launch_bounds__(256) void bfsplit_kernel(const float* __restrict__ in,
                                                      ushort* __restrict__ oh,
                                                      ushort* __restrict__ ol) {
  int i = (blockIdx.x * 256 + threadIdx.x) * 4;
  f32x4 v = *(const f32x4*)&in[i];
  ushort h[4], l[4];
#pragma unroll
  for (int j = 0; j < 4; j++) { h[j] = f2bf(v[j]); l[j] = f2bf(v[j] - bf2f(h[j])); }
  *(s16x4*)&oh[i] = *(const s16x4*)h;
  *(s16x4*)&ol[i] = *(const s16x4*)l;
}

// ---------------------------------------------------------------------------
// Fused expert GEMM (r11 structure, 128x128, depth-2 register prefetch).
// ---------------------------------------------------------------------------
#define MM_FEXP_LOAD(ra0v, ra1v, rb0v, rb1v, rb2v, rb3v, T)            \
  { int _ko = (T) * 32;                                                \
    ra0v = *(const short8*)(aG[0] + _ko);                              \
    ra1v = *(const short8*)(aG[1] + _ko);                              \
    rb0v = *(const f32x4*)(bG + (size_t)(_ko + 0) * N);                \
    rb1v = *(const f32x4*)(bG + (size_t)(_ko + 1) * N);                \
    rb2v = *(const f32x4*)(bG + (size_t)(_ko + 2) * N);                \
    rb3v = *(const f32x4*)(bG + (size_t)(_ko + 3) * N); }

#define MM_FEXP_STAGE(buf, ra0v, ra1v, rb0v, rb1v, rb2v, rb3v)         \
  { *(short8*)&As[buf][aw[0]] = ra0v;                                  \
    *(short8*)&As[buf][aw[1]] = ra1v;                                  \
    _Pragma("unroll")                                                  \
    for (int i = 0; i < 4; i++) {                                      \
      ushort u[4];                                                     \
      u[0] = f2bf(rb0v[i]); u[1] = f2bf(rb1v[i]);                      \
      u[2] = f2bf(rb2v[i]); u[3] = f2bf(rb3v[i]);                      \
      *(s16x4*)&Bs[buf][(nb * 4 + i) * 40 + bslot * 4] = *(const s16x4*)u; } }

#define MM_FEXP_MFMA(buf)                                              \
  { short8 af[4], bf[4];                                               \
    _Pragma("unroll")                                                  \
    for (int mi = 0; mi < 4; mi++) af[mi] = *(const short8*)&As[buf][aro[mi]]; \
    _Pragma("unroll")                                                  \
    for (int ni = 0; ni < 4; ni++) bf[ni] = *(const short8*)&Bs[buf][bro[ni]]; \
    _Pragma("unroll")                                                  \
    for (int mi = 0; mi < 4; mi++)                                     \
      _Pragma("unroll")                                                \
      for (int ni = 0; ni < 4; ni++)                                   \
        acc[mi][ni] = __builtin_amdgcn_mfma_f32_16x16x32_bf16(af[mi], bf[ni], acc[mi][ni], 0, 0, 0); }

template <int EPI, int KSPLIT>
__global__ __launch_bounds__(256) void mm_fexp(
    const ushort* __restrict__ A, const float* __restrict__ Bf,
    const float* __restrict__ bias, void* __restrict__ Cout,
    const int* __restrict__ tok, const int* __restrict__ offcnt,
    int N, int K)
{
  int zz = blockIdx.z;
  int e  = (KSPLIT > 1) ? (zz & (NE - 1)) : zz;
  int ks = (KSPLIT > 1) ? (zz >> 3) : 0;
  int off = offcnt[e], cnt = offcnt[NE + e];
  int m0 = blockIdx.y * 128;
  if (m0 >= cnt) return;
  int n0 = blockIdx.x * 128;
  const float* Bp = Bf + (size_t)e * K * N;
  const int Kc = K / KSPLIT, kbase = ks * Kc;

  __shared__ __align__(16) ushort As[2][128 * 32];
  __shared__ __align__(16) ushort Bs[2][128 * 40];

  int t = threadIdx.x, lane = t & 63, w = t >> 6, wr = w >> 1, wc = w & 1;

  const ushort* aG[2]; int aw[2];
#pragma unroll
  for (int c = 0; c < 2; c++) {
    int gid = w * 128 + c * 64 + lane;
    int m = gid >> 2, p = gid & 3;
    int kg = p ^ ((m >> 1) & 3);
    int mc = m0 + m; if (mc > cnt - 1) mc = cnt - 1;
    int arow = tok ? tok[off + mc] : (off + mc);
    aG[c] = A + (size_t)arow * K + kbase + kg * 8;
    aw[c] = gid * 8;
  }

  int kb = t >> 5, nb = t & 31;
  const float* bG = Bp + (size_t)(kbase + kb * 4) * N + n0 + nb * 4;
  int bslot = kb ^ ((nb & 3) << 1);

  int aro[4], bro[4];
#pragma unroll
  for (int mi = 0; mi < 4; mi++) {
    int m = wr * 64 + mi * 16 + (lane & 15);
    aro[mi] = (m * 4 + ((lane >> 4) ^ ((m >> 1) & 3))) * 8;
  }
#pragma unroll
  for (int ni = 0; ni < 4; ni++) {
    int n = wc * 64 + ni * 16 + (lane & 15);
    bro[ni] = n * 40 + ((((lane >> 4) * 2) ^ (((n >> 2) & 3) << 1))) * 4;
  }

  f32x4 acc[4][4] = {};
  const int nt = Kc / 32;

  short8 raA0, raA1, raB0, raB1;
  f32x4 rbA0, rbA1, rbA2, rbA3, rbB0, rbB1, rbB2, rbB3;
  MM_FEXP_LOAD(raA0, raA1, rbA0, rbA1, rbA2, rbA3, 0);
  MM_FEXP_LOAD(raB0, raB1, rbB0, rbB1, rbB2, rbB3, 1);

  for (int tt = 0; tt < nt; tt += 2) {
    MM_FEXP_STAGE(0, raA0, raA1, rbA0, rbA1, rbA2, rbA3);
    if (tt + 2 < nt) MM_FEXP_LOAD(raA0, raA1, rbA0, rbA1, rbA2, rbA3, tt + 2);
    asm volatile("s_waitcnt lgkmcnt(0)" ::: "memory");
    __builtin_amdgcn_sched_barrier(0);
    __builtin_amdgcn_s_barrier();
    MM_FEXP_MFMA(0);
    MM_FEXP_STAGE(1, raB0, raB1, rbB0, rbB1, rbB2, rbB3);
    if (tt + 3 < nt) MM_FEXP_LOAD(raB0, raB1, rbB0, rbB1, rbB2, rbB3, tt + 3);
    asm volatile("s_waitcnt lgkmcnt(0)" ::: "memory");
    __builtin_amdgcn_sched_barrier(0);
    __builtin_amdgcn_s_barrier();
    MM_FEXP_MFMA(1);
  }

  const float* biasp = (EPI == 3) ? nullptr : bias + (size_t)e * N;
  float* Cp = (float*)Cout + (size_t)ks * 2048 * N;
#pragma unroll
  for (int mi = 0; mi < 4; mi++) {
#pragma unroll
    for (int j = 0; j < 4; j++) {
      int grow = m0 + wr * 64 + mi * 16 + (lane >> 4) * 4 + j;
      if (grow >= cnt) continue;
      size_t rbase = (size_t)(off + grow) * N;
#pragma unroll
      for (int ni = 0; ni < 4; ni++) {
        int gcol = n0 + wc * 64 + ni * 16 + (lane & 15);
        float v = acc[mi][ni][j];
        if (EPI == 1) ((ushort*)Cout)[rbase + gcol] = f2bf(gelu_fast(v + biasp[gcol]));
        else          Cp[rbase + gcol] = v;
      }
    }
  }
}

#undef MM_FEXP_LOAD
#undef MM_FEXP_STAGE
#undef MM_FEXP_MFMA

// ---------------------------------------------------------------------------
// Split-precision GEMM (pre-router path).
// ---------------------------------------------------------------------------
__global__ __launch_bounds__(256) void mm_split(
    const ushort* __restrict__ Ah, const ushort* __restrict__ Al,
    const ushort* __restrict__ Bh, const ushort* __restrict__ Bl,
    float* __restrict__ C, int N, int K)
{
  int m0 = blockIdx.y * 128;
  int n0 = blockIdx.x * 128;

  __shared__ __align__(16) ushort Ahs[2][4096], Als[2][4096];
  __shared__ __align__(16) ushort Bhs[2][4096], Bls[2][4096];

  int t = threadIdx.x, lane = t & 63, w = t >> 6, wr = w >> 1, wc = w & 1;

  const ushort *aGh[2], *aGl[2], *bGh[2], *bGl[2];
  int lofs[2];
#pragma unroll
  for (int c = 0; c < 2; c++) {
    int gid = w * 128 + c * 64 + lane;
    int m = gid >> 2, p = gid & 3;
    int kg = p ^ ((m >> 1) & 3);
    aGh[c] = Ah + (size_t)(m0 + m) * K + kg * 8;
    aGl[c] = Al + (size_t)(m0 + m) * K + kg * 8;
    bGh[c] = Bh + (size_t)(n0 + m) * K + kg * 8;
    bGl[c] = Bl + (size_t)(n0 + m) * K + kg * 8;
    lofs[c] = (w * 128 + c * 64) * 8;
  }

  int aro[4], bro[4];
#pragma unroll
  for (int mi = 0; mi < 4; mi++) {
    int m = wr * 64 + mi * 16 + (lane & 15);
    aro[mi] = (m * 4 + ((lane >> 4) ^ ((m >> 1) & 3))) * 8;
  }
#pragma unroll
  for (int ni = 0; ni < 4; ni++) {
    int n = wc * 64 + ni * 16 + (lane & 15);
    bro[ni] = (n * 4 + ((lane >> 4) ^ ((n >> 1) & 3))) * 8;
  }

  f32x4 acc[4][4] = {};
  const int nt = K / 32;

#pragma unroll
  for (int c = 0; c < 2; c++) {
    gl2lds16(aGh[c], &Ahs[0][lofs[c]]); gl2lds16(aGl[c], &Als[0][lofs[c]]);
    gl2lds16(bGh[c], &Bhs[0][lofs[c]]); gl2lds16(bGl[c], &Bls[0][lofs[c]]);
  }
  if (nt > 1) {
#pragma unroll
    for (int c = 0; c < 2; c++) {
      gl2lds16(aGh[c] + 32, &Ahs[1][lofs[c]]); gl2lds16(aGl[c] + 32, &Als[1][lofs[c]]);
      gl2lds16(bGh[c] + 32, &Bhs[1][lofs[c]]); gl2lds16(bGl[c] + 32, &Bls[1][lofs[c]]);
    }
  }

  for (int tt = 0; tt < nt; tt++) {
    if (tt + 1 < nt) WAIT_VM(8); else WAIT_VM(0);
    __builtin_amdgcn_s_barrier();
    int b = tt & 1;
    short8 ah[4], al_[4], bh[4], bl_[4];
#pragma unroll
    for (int mi = 0; mi < 4; mi++) {
      ah[mi] = *(const short8*)&Ahs[b][aro[mi]];
      al_[mi] = *(const short8*)&Als[b][aro[mi]];
    }
#pragma unroll
    for (int ni = 0; ni < 4; ni++) {
      bh[ni] = *(const short8*)&Bhs[b][bro[ni]];
      bl_[ni] = *(const short8*)&Bls[b][bro[ni]];
    }
#pragma unroll
    for (int mi = 0; mi < 4; mi++)
#pragma unroll
      for (int ni = 0; ni < 4; ni++) {
        acc[mi][ni] = __builtin_amdgcn_mfma_f32_16x16x32_bf16(al_[mi], bh[ni], acc[mi][ni], 0, 0, 0);
        acc[mi][ni] = __builtin_amdgcn_mfma_f32_16x16x32_bf16(ah[mi], bl_[ni], acc[mi][ni], 0, 0, 0);
        acc[mi][ni] = __builtin_amdgcn_mfma_f32_16x16x32_bf16(ah[mi], bh[ni], acc[mi][ni], 0, 0, 0);
      }
    asm volatile("s_waitcnt lgkmcnt(0)" ::: "memory");
    __builtin_amdgcn_sched_barrier(0);
    __builtin_amdgcn_s_barrier();
    if (tt + 2 < nt) {
      int ko = (tt + 2) * 32;
#pragma unroll
      for (int c = 0; c < 2; c++) {
        gl2lds16(aGh[c] + ko, &Ahs[b][lofs[c]]); gl2lds16(aGl[c] + ko, &Als[b][lofs[c]]);
        gl2lds16(bGh[c] + ko, &Bhs[b][lofs[c]]); gl2lds16(bGl[c] + ko, &Bls[b][lofs[c]]);
      }
    }
  }

#pragma unroll
  for (int mi = 0; mi < 4; mi++)
#pragma unroll
    for (int j = 0; j < 4; j++) {
      int grow = m0 + wr * 64 + mi * 16 + (lane >> 4) * 4 + j;
      size_t rbase = (size_t)grow * N;
#pragma unroll
      for (int ni = 0; ni < 4; ni++) {
        int gcol = n0 + wc * 64 + ni * 16 + (lane & 15);
        C[rbase + gcol] = acc[mi][ni][j];
      }
    }
}

// ---------------------------------------------------------------------------
// bf16-MFMA GEMM with in-loop conversion (fallback path only).
// ---------------------------------------------------------------------------
template <int EPI, int SPLIT>
__global__ __launch_bounds__(256) void mm_bf16(
    const float* __restrict__ A, const float* __restrict__ B,
    const float* __restrict__ bias, float* __restrict__ C,
    const int* __restrict__ tok, const int* __restrict__ offcnt,
    int M, int N, int K)
{
  int e = blockIdx.z;
  int off = 0, cnt = M;
  if (offcnt) { off = offcnt[e]; cnt = offcnt[NE + e]; }
  int m0 = blockIdx.y * 128;
  if (m0 >= cnt) return;
  const float* Bp = B + (size_t)e * K * N;
  const float* biasp = (EPI == 0) ? nullptr : bias + (size_t)e * N;
  int n0 = blockIdx.x * 128;

  __shared__ __align__(16) ushort As[(SPLIT + 1) * 128 * 32];
  __shared__ __align__(16) ushort Bs[(SPLIT + 1) * 128 * 32];

  int t = threadIdx.x;
  int lane = t & 63;
  int w = t >> 6, wr = w >> 1, wc = w & 1;

  const float* aptr[2];
  int aws[2];
  for (int i = 0; i < 2; i++) {
    int mr = i * 64 + (t >> 2);
    int mc = m0 + mr; if (mc > cnt - 1) mc = cnt - 1;
    int arow = tok ? tok[off + mc] : (off + mc);
    aptr[i] = A + (size_t)arow * K + (t & 3) * 8;
    aws[i] = mr * 32 + (t & 3) * 8;
  }

  int bn = t >> 1, bkh = (t & 1) * 16;
  const float* bptr = Bp + (size_t)bkh * N + n0 + bn;
  int bws0 = bn * 32 + 8 * (((bkh >> 3) + 0) ^ (bn & 3));
  int bws1 = bn * 32 + 8 * (((bkh >> 3) + 1) ^ (bn & 3));

  int aro[4], bro[4];
#pragma unroll
  for (int mi = 0; mi < 4; mi++)
    aro[mi] = (wr * 64 + mi * 16 + (lane & 15)) * 32 + (lane >> 4) * 8;
#pragma unroll
  for (int ni = 0; ni < 4; ni++) {
    int n = wc * 64 + ni * 16 + (lane & 15);
    bro[ni] = n * 32 + 8 * ((lane >> 4) ^ (n & 3));
  }

  f32x4 acc[4][4] = {};

  for (int k0 = 0; k0 < K; k0 += 32) {
#pragma unroll
    for (int i = 0; i < 2; i++) {
      f32x4 v0 = *(const f32x4*)(aptr[i] + k0);
      f32x4 v1 = *(const f32x4*)(aptr[i] + k0 + 4);
      ushort uh[8], ul[8];
#pragma unroll
      for (int j = 0; j < 4; j++) {
        float f0 = v0[j], f1 = v1[j];
        ushort h0 = f2bf(f0), h1 = f2bf(f1);
        uh[j] = h0; uh[4 + j] = h1;
        if (SPLIT) { ul[j] = f2bf(f0 - bf2f(h0)); ul[4 + j] = f2bf(f1 - bf2f(h1)); }
      }
      *(short8*)&As[aws[i]] = *(const short8*)uh;
      if (SPLIT) *(short8*)&As[4096 + aws[i]] = *(const short8*)ul;
    }
    {
      const float* bp = bptr + (size_t)k0 * N;
      ushort uh[16], ul[16];
#pragma unroll
      for (int i = 0; i < 16; i++) {
        float f = bp[(size_t)i * N];
        ushort h = f2bf(f);
        uh[i] = h;
        if (SPLIT) ul[i] = f2bf(f - bf2f(h));
      }
      *(short8*)&Bs[bws0] = *(const short8*)&uh[0];
      *(short8*)&Bs[bws1] = *(const short8*)&uh[8];
      if (SPLIT) {
        *(short8*)&Bs[4096 + bws0] = *(const short8*)&ul[0];
        *(short8*)&Bs[4096 + bws1] = *(const short8*)&ul[8];
      }
    }
    __syncthreads();
    short8 afh[4], bfh[4], afl[4], bfl[4];
#pragma unroll
    for (int mi = 0; mi < 4; mi++) {
      afh[mi] = *(const short8*)&As[aro[mi]];
      if (SPLIT) afl[mi] = *(const short8*)&As[4096 + aro[mi]];
    }
#pragma unroll
    for (int ni = 0; ni < 4; ni++) {
      bfh[ni] = *(const short8*)&Bs[bro[ni]];
      if (SPLIT) bfl[ni] = *(const short8*)&Bs[4096 + bro[ni]];
    }
#pragma unroll
    for (int mi = 0; mi < 4; mi++)
#pragma unroll
      for (int ni = 0; ni < 4; ni++) {
        if (SPLIT) {
          acc[mi][ni] = __builtin_amdgcn_mfma_f32_16x16x32_bf16(afl[mi], bfh[ni], acc[mi][ni], 0, 0, 0);
          acc[mi][ni] = __builtin_amdgcn_mfma_f32_16x16x32_bf16(afh[mi], bfl[ni], acc[mi][ni], 0, 0, 0);
        }
        acc[mi][ni] = __builtin_amdgcn_mfma_f32_16x16x32_bf16(afh[mi], bfh[ni], acc[mi][ni], 0, 0, 0);
      }
    __syncthreads();
  }

#pragma unroll
  for (int mi = 0; mi < 4; mi++) {
#pragma unroll
    for (int j = 0; j < 4; j++) {
      int grow = m0 + wr * 64 + mi * 16 + (lane >> 4) * 4 + j;
      if (grow >= cnt) continue;
      size_t rbase = (size_t)(off + grow) * N;
#pragma unroll
      for (int ni = 0; ni < 4; ni++) {
        int gcol = n0 + wc * 64 + ni * 16 + (lane & 15);
        float v = acc[mi][ni][j];
        if (EPI >= 1) v += biasp[gcol];
        if (EPI == 1) v = gelu_tanh(v);
        C[rbase + gcol] = v;
      }
    }
  }
}

// ---------------------------------------------------------------------------
// MFMA flash attention, split-bf16, KV-chunked (NCH chunks per q-block).
// ---------------------------------------------------------------------------
__device__ __forceinline__ int vidx(int d, int key) {
  return d * 64 + ((((key >> 3) ^ (d & 7)) << 3) | (key & 7));
}

__global__ __launch_bounds__(256, 1) void attn_mfma(const float* __restrict__ qkv,
                                                    float* __restrict__ opart,
                                                    float* __restrict__ ml) {
  const int qb = blockIdx.x;
  const int ch = blockIdx.y;
  const int head = blockIdx.z;
  const int q0 = qb * 128;
  const int t = threadIdx.x;
  const int lane = t & 63, w = t >> 6;
  const int g = lane >> 4, l4 = lane & 15;

  __shared__ __align__(16) ushort Kh[64 * 64], Kl[64 * 64];
  __shared__ __align__(16) ushort Vh[64 * 64], Vl[64 * 64];
  __shared__ __align__(16) ushort Ph[4][32 * 72], Pl[4][32 * 72];

  short8 qh[2][2], ql[2][2];
#pragma unroll
  for (int mi = 0; mi < 2; mi++)
#pragma unroll
    for (int ks = 0; ks < 2; ks++) {
      int row = q0 + w * 32 + mi * 16 + l4;
      const float* qp = qkv + (size_t)row * 3072 + head * 64 + ks * 32 + g * 8;
      f32x4 a = *(const f32x4*)qp;
      f32x4 b4 = *(const f32x4*)(qp + 4);
      ushort uh[8], ul_[8];
#pragma unroll
      for (int j = 0; j < 4; j++) {
        ushort h0 = f2bf(a[j]), h1 = f2bf(b4[j]);
        uh[j] = h0; uh[4 + j] = h1;
        ul_[j] = f2bf(a[j] - bf2f(h0)); ul_[4 + j] = f2bf(b4[j] - bf2f(h1));
      }
      qh[mi][ks] = *(const short8*)uh;
      ql[mi][ks] = *(const short8*)ul_;
    }

  float m_s[2][4], l_s[2][4];
  f32x4 O[2][4] = {};
#pragma unroll
  for (int mi = 0; mi < 2; mi++)
#pragma unroll
    for (int j = 0; j < 4; j++) { m_s[mi][j] = -1e30f; l_s[mi][j] = 0.f; }

  const int ntot = 2 * (qb + 1);
  const int kt_beg = (ch * ntot) / NCH;
  const int kt_end = ((ch + 1) * ntot) / NCH;
  for (int kt = kt_beg; kt < kt_end; kt++) {
    const int kv0 = kt * 64;
    __syncthreads();
    {
      int key = t >> 2;
      int dblk = (t & 3) * 16;
      const float* kp = qkv + (size_t)(kv0 + key) * 3072 + 1024 + head * 64 + dblk;
      const float* vp = kp + 1024;
      f32x4 k0 = *(const f32x4*)kp, k1 = *(const f32x4*)(kp + 4),
            k2 = *(const f32x4*)(kp + 8), k3 = *(const f32x4*)(kp + 12);
      f32x4 v0 = *(const f32x4*)vp, v1 = *(const f32x4*)(vp + 4),
            v2 = *(const f32x4*)(vp + 8), v3 = *(const f32x4*)(vp + 12);
      float kf[16] = {k0[0],k0[1],k0[2],k0[3], k1[0],k1[1],k1[2],k1[3],
                      k2[0],k2[1],k2[2],k2[3], k3[0],k3[1],k3[2],k3[3]};
      float vf[16] = {v0[0],v0[1],v0[2],v0[3], v1[0],v1[1],v1[2],v1[3],
                      v2[0],v2[1],v2[2],v2[3], v3[0],v3[1],v3[2],v3[3]};
#pragma unroll
      for (int half = 0; half < 2; half++) {
        int d8 = (dblk >> 3) + half;
        int idx = key * 64 + ((d8 ^ (key & 7)) << 3);
        ushort uh[8], ul_[8];
#pragma unroll
        for (int j = 0; j < 8; j++) {
          float f = kf[half * 8 + j];
          ushort h = f2bf(f);
          uh[j] = h; ul_[j] = f2bf(f - bf2f(h));
        }
        *(short8*)&Kh[idx] = *(const short8*)uh;
        *(short8*)&Kl[idx] = *(const short8*)ul_;
      }
#pragma unroll
      for (int i = 0; i < 16; i++) {
        int d = dblk + i;
        int idx = vidx(d, key);
        float f = vf[i];
        ushort h = f2bf(f);
        Vh[idx] = h; Vl[idx] = f2bf(f - bf2f(h));
      }
    }
    __syncthreads();

    if (kv0 <= q0 + w * 32 + 31) {
      f32x4 S[2][4] = {};
#pragma unroll
      for (int ks = 0; ks < 2; ks++) {
        short8 kbh[4], kbl[4];
#pragma unroll
        for (int ni = 0; ni < 4; ni++) {
          int key = ni * 16 + l4;
          int d8 = ks * 4 + g;
          int idx = key * 64 + ((d8 ^ (key & 7)) << 3);
          kbh[ni] = *(const short8*)&Kh[idx];
          kbl[ni] = *(const short8*)&Kl[idx];
        }
#pragma unroll
        for (int mi = 0; mi < 2; mi++)
#pragma unroll
          for (int ni = 0; ni < 4; ni++) {
            S[mi][ni] = __builtin_amdgcn_mfma_f32_16x16x32_bf16(ql[mi][ks], kbh[ni], S[mi][ni], 0, 0, 0);
            S[mi][ni] = __builtin_amdgcn_mfma_f32_16x16x32_bf16(qh[mi][ks], kbl[ni], S[mi][ni], 0, 0, 0);
            S[mi][ni] = __builtin_amdgcn_mfma_f32_16x16x32_bf16(qh[mi][ks], kbh[ni], S[mi][ni], 0, 0, 0);
          }
      }
#pragma unroll
      for (int mi = 0; mi < 2; mi++) {
        int rowb = q0 + w * 32 + mi * 16 + g * 4;
        float mx[4] = {-1e30f, -1e30f, -1e30f, -1e30f};
#pragma unroll
        for (int ni = 0; ni < 4; ni++) {
          int col = kv0 + ni * 16 + l4;
#pragma unroll
          for (int j = 0; j < 4; j++) {
            float s = S[mi][ni][j] * 0.125f;
            if (col > rowb + j) s = -1e30f;
            S[mi][ni][j] = s;
            mx[j] = fmaxf(mx[j], s);
          }
        }
#pragma unroll
        for (int j = 0; j < 4; j++) {
#pragma unroll
          for (int msk = 8; msk; msk >>= 1) mx[j] = fmaxf(mx[j], __shfl_xor(mx[j], msk));
          float mn = fmaxf(m_s[mi][j], mx[j]);
          float sc = __expf(m_s[mi][j] - mn);
          m_s[mi][j] = mn;
          l_s[mi][j] *= sc;
#pragma unroll
          for (int df = 0; df < 4; df++) O[mi][df][j] *= sc;
        }
        float ps[4] = {0.f, 0.f, 0.f, 0.f};
#pragma unroll
        for (int ni = 0; ni < 4; ni++)
#pragma unroll
          for (int j = 0; j < 4; j++) {
            float p = __expf(S[mi][ni][j] - m_s[mi][j]);
            ps[j] += p;
            int rl = mi * 16 + g * 4 + j, cl = ni * 16 + l4;
            ushort h = f2bf(p);
            Ph[w][rl * 72 + cl] = h;
            Pl[w][rl * 72 + cl] = f2bf(p - bf2f(h));
          }
#pragma unroll
        for (int j = 0; j < 4; j++) {
#pragma unroll
          for (int msk = 8; msk; msk >>= 1) ps[j] += __shfl_xor(ps[j], msk);
          l_s[mi][j] += ps[j];
        }
      }
      asm volatile("s_waitcnt lgkmcnt(0)" ::: "memory");
      __builtin_amdgcn_sched_barrier(0);
#pragma unroll
      for (int ks = 0; ks < 2; ks++) {
        short8 pah[2], pal[2], vbh[4], vbl[4];
#pragma unroll
        for (int mi = 0; mi < 2; mi++) {
          int idx = (mi * 16 + l4) * 72 + ks * 32 + g * 8;
          pah[mi] = *(const short8*)&Ph[w][idx];
          pal[mi] = *(const short8*)&Pl[w][idx];
        }
#pragma unroll
        for (int df = 0; df < 4; df++) {
          int d = df * 16 + l4;
          int k8 = ks * 4 + g;
          int idx = d * 64 + ((k8 ^ (d & 7)) << 3);
          vbh[df] = *(const short8*)&Vh[idx];
          vbl[df] = *(const short8*)&Vl[idx];
        }
#pragma unroll
        for (int mi = 0; mi < 2; mi++)
#pragma unroll
          for (int df = 0; df < 4; df++) {
            O[mi][df] = __builtin_amdgcn_mfma_f32_16x16x32_bf16(pal[mi], vbh[df], O[mi][df], 0, 0, 0);
            O[mi][df] = __builtin_amdgcn_mfma_f32_16x16x32_bf16(pah[mi], vbl[df], O[mi][df], 0, 0, 0);
            O[mi][df] = __builtin_amdgcn_mfma_f32_16x16x32_bf16(pah[mi], vbh[df], O[mi][df], 0, 0, 0);
          }
      }
    }
  }

  // ---- write partials ----
#pragma unroll
  for (int mi = 0; mi < 2; mi++)
#pragma unroll
    for (int j = 0; j < 4; j++) {
      int row = q0 + w * 32 + mi * 16 + g * 4 + j;
      if (l4 == 0) {
        float* mlp = ml + (((size_t)ch * NH + head) * SEQ + row) * 2;
        mlp[0] = m_s[mi][j];
        mlp[1] = l_s[mi][j];
      }
#pragma unroll
      for (int df = 0; df < 4; df++)
        opart[(size_t)ch * (SEQ * DIM) + (size_t)row * DIM + head * 64 + df * 16 + l4] =
            O[mi][df][j];
    }
}

// ---- combine NCH KV-chunk partials -> bf16 hi/lo (fast) or fp32 (fallback) --
template <int SPLIT>
__global__ __launch_bounds__(256) void attn_combine(const float* __restrict__ opart,
                                                    const float* __restrict__ ml,
                                                    float* __restrict__ o,
                                                    ushort* __restrict__ oh,
                                                    ushort* __restrict__ ol) {
  int row = blockIdx.x, t = threadIdx.x;
  int d0 = t * 4;
  int head = d0 >> 6;
  float m[NCH], l[NCH];
#pragma unroll
  for (int ch = 0; ch < NCH; ch++) {
    const float* p = ml + (((size_t)ch * NH + head) * SEQ + row) * 2;
    m[ch] = p[0]; l[ch] = p[1];
  }
  float M = m[0];
#pragma unroll
  for (int ch = 1; ch < NCH; ch++) M = fmaxf(M, m[ch]);
  float wgt[NCH], den = 0.f;
#pragma unroll
  for (int ch = 0; ch < NCH; ch++) { wgt[ch] = __expf(m[ch] - M); den += l[ch] * wgt[ch]; }
  float inv = 1.f / den;
  f32x4 r = {0.f, 0.f, 0.f, 0.f};
#pragma unroll
  for (int ch = 0; ch < NCH; ch++) {
    f32x4 O = *(const f32x4*)&opart[(size_t)ch * (SEQ * DIM) + (size_t)row * DIM + d0];
#pragma unroll
    for (int j = 0; j < 4; j++) r[j] += O[j] * wgt[ch];
  }
#pragma unroll
  for (int j = 0; j < 4; j++) r[j] *= inv;
  if (SPLIT) {
    ushort hh[4], ll[4];
#pragma unroll
    for (int j = 0; j < 4; j++) { hh[j] = f2bf(r[j]); ll[j] = f2bf(r[j] - bf2f(hh[j])); }
    *(s16x4*)&oh[(size_t)row * DIM + d0] = *(const s16x4*)hh;
    *(s16x4*)&ol[(size_t)row * DIM + d0] = *(const s16x4*)ll;
  } else {
    *(f32x4*)&o[(size_t)row * DIM + d0] = r;
  }
}

// ---------------- block reduce helper ----------------
__device__ float block_reduce_256(float v, float* red, int t) {
  red[t] = v; __syncthreads();
  for (int st = 128; st > 0; st >>= 1) {
    if (t < st) red[t] += red[t + st];
    __syncthreads();
  }
  float r = red[0];
  __syncthreads();
  return r;
}

// ---- h = LN(x + r) * g + b, bf16 copy, + fused router top-2 (fast path) ----
__global__ __launch_bounds__(256) void addln_router_kernel(
    const float* __restrict__ x, const float* __restrict__ r,
    const float* __restrict__ g, const float* __restrict__ b,
    const float* __restrict__ wg,
    float* __restrict__ out, ushort* __restrict__ outb,
    int* __restrict__ topi, float* __restrict__ topw) {
  __shared__ float red[256];
  __shared__ float red2[NE][256];
  int row = blockIdx.x, t = threadIdx.x;
  float vals[4];
  float s = 0.f;
  for (int i = 0; i < 4; i++) {
    int d = t + i * 256;
    vals[i] = x[(size_t)row * DIM + d] + r[(size_t)row * DIM + d];
    s += vals[i];
  }
  float mean = block_reduce_256(s, red, t) * (1.f / DIM);
  float vs = 0.f;
  for (int i = 0; i < 4; i++) { float d = vals[i] - mean; vs += d * d; }
  float var = block_reduce_256(vs, red, t) * (1.f / DIM);
  float inv = rsqrtf(var + 1e-5f);
  float hv4[4];
  for (int i = 0; i < 4; i++) {
    int d = t + i * 256;
    float v = (vals[i] - mean) * inv * g[d] + b[d];
    hv4[i] = v;
    out[(size_t)row * DIM + d] = v;
    outb[(size_t)row * DIM + d] = f2bf(v);
  }
  float acc[NE] = {};
  for (int i = 0; i < 4; i++) {
    int d = t + i * 256;
    const float* wr = wg + (size_t)d * NE;
    for (int e = 0; e < NE; e++) acc[e] += hv4[i] * wr[e];
  }
  for (int e = 0; e < NE; e++) red2[e][t] = acc[e];
  __syncthreads();
  for (int st = 128; st > 0; st >>= 1) {
    if (t < st)
      for (int e = 0; e < NE; e++) red2[e][t] += red2[e][t + st];
    __syncthreads();
  }
  if (t == 0) {
    float l[NE];
    for (int e = 0; e < NE; e++) l[e] = red2[e][0];
    int i0 = 0;
    for (int e = 1; e < NE; e++) if (l[e] > l[i0]) i0 = e;
    int i1 = -1;
    for (int e = 0; e < NE; e++) {
      if (e == i0) continue;
      if (i1 < 0 || l[e] > l[i1]) i1 = e;
    }
    float p1 = __expf(l[i1] - l[i0]);
    float iv = 1.f / (1.f + p1);
    topi[row * 2] = i0; topi[row * 2 + 1] = i1;
    topw[row * 2] = iv; topw[row * 2 + 1] = p1 * iv;
  }
}

// ---------------- h = LN(x + r) * g + b  (fallback) ----------------
__global__ __launch_bounds__(256) void addln_kernel(const float* __restrict__ x,
                                                    const float* __restrict__ r,
                                                    const float* __restrict__ g,
                                                    const float* __restrict__ b,
                                                    float* __restrict__ out,
                                                    ushort* __restrict__ outb) {
  __shared__ float red[256];
  int row = blockIdx.x, t = threadIdx.x;
  float vals[4];
  float s = 0.f;
  for (int i = 0; i < 4; i++) {
    int d = t + i * 256;
    vals[i] = x[(size_t)row * DIM + d] + r[(size_t)row * DIM + d];
    s += vals[i];
  }
  float mean = block_reduce_256(s, red, t) * (1.f / DIM);
  float vs = 0.f;
  for (int i = 0; i < 4; i++) { float d = vals[i] - mean; vs += d * d; }
  float var = block_reduce_256(vs, red, t) * (1.f / DIM);
  float inv = rsqrtf(var + 1e-5f);
  for (int i = 0; i < 4; i++) {
    int d = t + i * 256;
    float v = (vals[i] - mean) * inv * g[d] + b[d];
    out[(size_t)row * DIM + d] = v;
    if (outb) outb[(size_t)row * DIM + d] = f2bf(v);
  }
}

// ---------------- router (fallback) ----------------
__global__ __launch_bounds__(256) void router_kernel(const float* __restrict__ h,
                                                     const float* __restrict__ wg,
                                                     int* __restrict__ topi,
                                                     float* __restrict__ topw) {
  __shared__ float red[NE][256];
  int tkn = blockIdx.x, t = threadIdx.x;
  float acc[NE] = {};
  for (int i = 0; i < 4; i++) {
    int d = t + i * 256;
    float hv = h[(size_t)tkn * DIM + d];
    const float* wr = wg + (size_t)d * NE;
    for (int e = 0; e < NE; e++) acc[e] += hv * wr[e];
  }
  for (int e = 0; e < NE; e++) red[e][t] = acc[e];
  __syncthreads();
  for (int st = 128; st > 0; st >>= 1) {
    if (t < st)
      for (int e = 0; e < NE; e++) red[e][t] += red[e][t + st];
    __syncthreads();
  }
  if (t == 0) {
    float l[NE];
    for (int e = 0; e < NE; e++) l[e] = red[e][0];
    int i0 = 0;
    for (int e = 1; e < NE; e++) if (l[e] > l[i0]) i0 = e;
    int i1 = -1;
    for (int e = 0; e < NE; e++) {
      if (e == i0) continue;
      if (i1 < 0 || l[e] > l[i1]) i1 = e;
    }
    float p1 = __expf(l[i1] - l[i0]);
    float inv = 1.f / (1.f + p1);
    topi[tkn * 2] = i0; topi[tkn * 2 + 1] = i1;
    topw[tkn * 2] = inv; topw[tkn * 2 + 1] = p1 * inv;
  }
}

// ---------------------------------------------------------------------------
// Deterministic compaction via wave ballot: 1024 threads = 16 waves.
// Identical token ordering to the scan version; 2 barriers per expert.
// ---------------------------------------------------------------------------
__global__ __launch_bounds__(1024) void compact_kernel(const int* __restrict__ topi,
                                                       int* __restrict__ tok,
                                                       int* __restrict__ assign_row,
                                                       int* __restrict__ offcnt) {
  __shared__ int wsum[16];
  int t = threadIdx.x, lane = t & 63, w = t >> 6;
  int i0 = topi[t * 2], i1 = topi[t * 2 + 1];
  int base = 0;
  for (int e = 0; e < NE; e++) {
    int which = (i0 == e) ? 0 : ((i1 == e) ? 1 : -1);
    unsigned long long mask = __ballot(which >= 0);
    unsigned long long lem = (lane == 63) ? ~0ULL : ((1ULL << (lane + 1)) - 1ULL);
    int incl = __popcll(mask & lem);
    if (lane == 0) wsum[w] = __popcll(mask);
    __syncthreads();
    int pre = 0, tot = 0;
    for (int i = 0; i < 16; i++) { if (i < w) pre += wsum[i]; tot += wsum[i]; }
    if (which >= 0) {
      int pos = base + pre + incl - 1;
      tok[pos] = t;
      assign_row[t * 2 + which] = pos;
    }
    if (t == 0) { offcnt[e] = base; offcnt[NE + e] = tot; }
    base += tot;
    __syncthreads();
  }
}

// ---------------- final: out = LN(h + combine(moe)) ----------------
template <int KS>
__global__ __launch_bounds__(256) void final_ln_kernel(const float* __restrict__ h,
                                                       const float* __restrict__ y,
                                                       const int* __restrict__ assign_row,
                                                       const float* __restrict__ topw,
                                                       const int* __restrict__ topi,
                                                       const float* __restrict__ bb2,
                                                       const float* __restrict__ g,
                                                       const float* __restrict__ b,
                                                       float* __restrict__ out) {
  __shared__ float red[256];
  int row = blockIdx.x, t = threadIdx.x;
  int r0 = assign_row[row * 2], r1 = assign_row[row * 2 + 1];
  float w0 = topw[row * 2], w1 = topw[row * 2 + 1];
  float vals[4];
  float s = 0.f;
  for (int i = 0; i < 4; i++) {
    int d = t + i * 256;
    float acc0 = 0.f, acc1 = 0.f;
#pragma unroll
    for (int p = 0; p < KS; p++) {
      acc0 += y[(size_t)p * 2048 * DIM + (size_t)r0 * DIM + d];
      acc1 += y[(size_t)p * 2048 * DIM + (size_t)r1 * DIM + d];
    }
    float v = h[(size_t)row * DIM + d] + w0 * acc0 + w1 * acc1;
    if (KS > 1) {
      int e0 = topi[row * 2], e1 = topi[row * 2 + 1];
      v += w0 * bb2[e0 * DIM + d] + w1 * bb2[e1 * DIM + d];
    }
    vals[i] = v;
    s += v;
  }
  float mean = block_reduce_256(s, red, t) * (1.f / DIM);
  float vs = 0.f;
  for (int i = 0; i < 4; i++) { float d = vals[i] - mean; vs += d * d; }
  float var = block_reduce_256(vs, red, t) * (1.f / DIM);
  float inv = rsqrtf(var + 1e-5f);
  for (int i = 0; i < 4; i++) {
    int d = t + i * 256;
    out[(size_t)row * DIM + d] = (vals[i] - mean) * inv * g[d] + b[d];
  }
}

extern "C" void kernel_launch(void* const* d_in, const int* in_sizes, int n_in,
                              void* d_out, int out_size, void* d_ws, size_t ws_size,
                              hipStream_t stream) {
  const float* x     = (const float*)d_in[0];
  const float* w_qkv = (const float*)d_in[1];
  const float* w_o   = (const float*)d_in[2];
  const float* g1    = (const float*)d_in[3];
  const float* b1    = (const float*)d_in[4];
  const float* wg    = (const float*)d_in[5];
  const float* w1    = (const float*)d_in[6];
  const float* bb1   = (const float*)d_in[7];
  const float* w2    = (const float*)d_in[8];
  const float* bb2   = (const float*)d_in[9];
  const float* g2    = (const float*)d_in[10];
  const float* b2    = (const float*)d_in[11];
  float* out = (float*)d_out;
  float* ws = (float*)d_ws;

  const bool fast = ws_size >= (size_t)46671872 * 4;

  if (fast) {
    float* qkv    = ws;                       // 3,145,728 f
    float* oproj  = ws + 4194304;             // 1,048,576 f
    float* h      = ws + 5242880;             // 1,048,576 f
    float* ybuf   = ws + 6291456;             // 2,097,152 f (xh/xl/oh/ol aliases)
    float* topw   = ws + 8388608;             // 2,048 f
    int*   ibase  = (int*)(ws + 8390656);     // 8,192 ints
    int* topi       = ibase;
    int* tok        = ibase + 2048;
    int* assign_row = ibase + 4096;
    int* offcnt     = ibase + 6144;
    ushort* hb  = (ushort*)(ws + 8398848);    // 1,048,576 us
    ushort* h1b = (ushort*)(ws + 8923136);    // 8,388,608 us
    ushort* wqT  = (ushort*)(ws + 13117440);  // 3,145,728 us
    ushort* wqTl = wqT + 3145728;             // 3,145,728 us
    ushort* woT  = wqT + 6291456;             // 1,048,576 us
    ushort* woTl = wqT + 7340032;             // 1,048,576 us  (ends at f 17,311,744)
    float* ypart = ws + 17311744;             // 8,388,608 f (32 MB)
    float* mlbuf = ws + 25700352;             // 262,144 f (NCH*NH*SEQ*2)
    ushort* xh = (ushort*)ybuf;               // activation split aliases
    ushort* xl = xh + 1048576;
    ushort* oh = xh + 2097152;
    ushort* ol = xh + 3145728;
    float* opart = ypart;                     // NCH x 1,048,576 f (exactly fills)

    // 0. weight convert/transpose + fused x split
    wconv_kernel<<<dim3(64, 16, 3), 256, 0, stream>>>(w_qkv, w_o, x,
                                                      wqT, wqTl, woT, woTl, xh, xl);
    // 1. qkv = x @ w_qkv  (pipelined split GEMM)
    mm_split<<<dim3(24, 8), 256, 0, stream>>>(xh, xl, wqT, wqTl, qkv, 3 * DIM, DIM);
    // 2. attention (8-way KV chunks: 1024 blocks) + fused combine/split
    attn_mfma<<<dim3(8, NCH, NH), 256, 0, stream>>>(qkv, opart, mlbuf);
    attn_combine<1><<<dim3(SEQ), 256, 0, stream>>>(opart, mlbuf, nullptr, oh, ol);
    // 3. oproj = attn_o @ w_o
    mm_split<<<dim3(8, 8), 256, 0, stream>>>(oh, ol, woT, woTl, oproj, DIM, DIM);
    // 4. h = LN(x + oproj) + bf16 copy + fused router
    addln_router_kernel<<<dim3(SEQ), 256, 0, stream>>>(x, oproj, g1, b1, wg,
                                                       h, hb, topi, topw);
    // 5. compaction (ballot-based)
    compact_kernel<<<dim3(1), 1024, 0, stream>>>(topi, tok, assign_row, offcnt);
    // 6. expert up+gelu -> bf16
    mm_fexp<1, 1><<<dim3(FF / 128, 8, NE), 256, 0, stream>>>(hb, w1, bb1, (void*)h1b,
                                                             tok, offcnt, FF, DIM);
    // 7. expert down, K-split 4 -> fp32 partials (overwrites opart; dead)
    mm_fexp<3, 4><<<dim3(DIM / 128, 8, NE * 4), 256, 0, stream>>>(h1b, w2, nullptr,
                                                                  (void*)ypart,
                                                                  nullptr, offcnt, DIM, FF);
    // 8. combine partials + bb2 + residual + LN
    final_ln_kernel<4><<<dim3(SEQ), 256, 0, stream>>>(h, ypart, assign_row, topw,
                                                      topi, bb2, g2, b2, out);
  } else {
    float* qkv    = ws;
    float* attn_o = ws + 3145728;
    float* oproj  = ws + 4194304;
    float* h      = ws + 5242880;
    float* h1     = ws + 6291456;              // 8,388,608 f
    float* ybuf   = ws + 14680064;
    float* topw   = ws + 16777216;
    int*   ibase  = (int*)(ws + 16779264);
    int* topi       = ibase;
    int* tok        = ibase + 2048;
    int* assign_row = ibase + 4096;
    int* offcnt     = ibase + 6144;
    float* opart = h1;                         // alias (dead until expert GEMMs)
    float* mlbuf = ybuf;                       // alias (dead until exp2)

    mm_bf16<0, 1><<<dim3(24, 8, 1), 256, 0, stream>>>(x, w_qkv, nullptr, qkv,
                                                      nullptr, nullptr, SEQ, 3 * DIM, DIM);
    attn_mfma<<<dim3(8, NCH, NH), 256, 0, stream>>>(qkv, opart, mlbuf);
    attn_combine<0><<<dim3(SEQ), 256, 0, stream>>>(opart, mlbuf, attn_o, nullptr, nullptr);
    mm_bf16<0, 1><<<dim3(8, 8, 1), 256, 0, stream>>>(attn_o, w_o, nullptr, oproj,
                                                     nullptr, nullptr, SEQ, DIM, DIM);
    addln_kernel<<<dim3(SEQ), 256, 0, stream>>>(x, oproj, g1, b1, h, nullptr);
    router_kernel<<<dim3(SEQ), 256, 0, stream>>>(h, wg, topi, topw);
    compact_kernel<<<dim3(1), 1024, 0, stream>>>(topi, tok, assign_row, offcnt);
    mm_bf16<1, 0><<<dim3(32, 8, NE), 256, 0, stream>>>(h, w1, bb1, h1,
                                                       tok, offcnt, SEQ, FF, DIM);
    mm_bf16<2, 0><<<dim3(8, 8, NE), 256, 0, stream>>>(h1, w2, bb2, ybuf,
                                                      nullptr, offcnt, SEQ, DIM, FF);
    final_ln_kernel<1><<<dim3(SEQ), 256, 0, stream>>>(h, ybuf, assign_row, topw,
                                                      nullptr, nullptr, g2, b2, out);
  }
}